// Round 5
// baseline (361.728 us; speedup 1.0000x reference)
//
#include <hip/hip_runtime.h>

typedef _Float16 half_t;
typedef __attribute__((ext_vector_type(8))) _Float16 f16x8;   // 8 fp16 = 4 VGPRs
typedef __attribute__((ext_vector_type(4))) _Float16 f16x4;
typedef __attribute__((ext_vector_type(4))) float f32x4;
typedef __attribute__((ext_vector_type(4))) float float4v;

__device__ __forceinline__ void gload_lds16(const void* g, void* l) {
  __builtin_amdgcn_global_load_lds(
      (const __attribute__((address_space(1))) void*)g,
      (__attribute__((address_space(3))) void*)l, 16, 0, 0);
}

// ---------------------------------------------------------------------------
// C = A (MxK, row-major fp16) * B (KxN) given Bt = B^T (NxK row-major fp16)
// MODE 0: C = acc ; MODE 1: C = (acc + bias[col]) * alpha
// MODE 2: C = acc + rowscale[row] * bias[col]
// MODE 3: atomicAdd f32 (split-K accumulate), no bias
// SK: split-K factor; blockIdx.z = batch * SK + kslice.
// ---------------------------------------------------------------------------
template<int BM, int BN, int WM, int WN, int OUTF16, int MODE, int SK>
__global__ __launch_bounds__(256, 2)
void gemm_bt(const half_t* __restrict__ A, const half_t* __restrict__ Bt,
             void* __restrict__ Cv, const float* __restrict__ bias,
             const float* __restrict__ rowscale,
             int M, int N, int K, int lda, int ldb, int ldc, float alpha,
             long sA, long sB, long sC)
{
  constexpr int FM = WM / 16, FN = WN / 16, CW = BN / WN;
  __shared__ __attribute__((aligned(16))) half_t As[BM * 32];
  __shared__ __attribute__((aligned(16))) half_t Bs[BN * 32];

  const int tid = threadIdx.x, w = tid >> 6, lane = tid & 63;
  const int wr = w / CW, wc = w % CW;
  const int z = blockIdx.z / SK, ks = blockIdx.z % SK;
  const half_t* Ab = A + (long)z * sA;
  const half_t* Bb = Bt + (long)z * sB;
  const int m0 = blockIdx.x * BM, n0 = blockIdx.y * BN;
  const int g = lane >> 4, cc = lane & 15;
  const int srow = lane >> 2, scol = (lane & 3) * 8;   // staging lane map

  const f32x4 zero = {0.f, 0.f, 0.f, 0.f};
  f32x4 acc[FM][FN];
#pragma unroll
  for (int i = 0; i < FM; ++i)
#pragma unroll
    for (int j = 0; j < FN; ++j) acc[i][j] = zero;

  const int kchunk = K / SK;
  for (int kt = ks * kchunk; kt < (ks + 1) * kchunk; kt += 32) {
#pragma unroll
    for (int j = 0; j < BM / 64; ++j) {
      const int bi = w * (BM / 64) + j;
      gload_lds16(Ab + (long)(m0 + bi * 16 + srow) * lda + kt + scol, &As[bi * 512]);
    }
#pragma unroll
    for (int j = 0; j < BN / 64; ++j) {
      const int bi = w * (BN / 64) + j;
      gload_lds16(Bb + (long)(n0 + bi * 16 + srow) * ldb + kt + scol, &Bs[bi * 512]);
    }
    __syncthreads();   // drains vmcnt -> staged data visible

    f16x8 af[FM], bf[FN];
#pragma unroll
    for (int i = 0; i < FM; ++i)
      af[i] = *(const f16x8*)&As[(wr * WM + i * 16 + cc) * 32 + g * 8];
#pragma unroll
    for (int j = 0; j < FN; ++j)
      bf[j] = *(const f16x8*)&Bs[(wc * WN + j * 16 + cc) * 32 + g * 8];
#pragma unroll
    for (int i = 0; i < FM; ++i)
#pragma unroll
      for (int j = 0; j < FN; ++j)
        acc[i][j] = __builtin_amdgcn_mfma_f32_16x16x32_f16(af[i], bf[j], acc[i][j], 0, 0, 0);
    __syncthreads();   // before next-tile staging overwrites LDS
  }

  const long coff = (long)z * sC;
#pragma unroll
  for (int i = 0; i < FM; ++i)
#pragma unroll
    for (int j = 0; j < FN; ++j)
#pragma unroll
      for (int r = 0; r < 4; ++r) {
        const int row = m0 + wr * WM + i * 16 + g * 4 + r;   // C/D: row=(l>>4)*4+reg
        const int col = n0 + wc * WN + j * 16 + cc;          //      col=l&15
        float v = acc[i][j][r];
        if (MODE == 1) v = (v + bias[col]) * alpha;
        if (MODE == 2) v = v + rowscale[row] * bias[col];
        if (MODE == 3) {
          atomicAdd(&((float*)Cv)[coff + (long)row * ldc + col], v);
        } else {
          if (OUTF16) ((half_t*)Cv)[coff + (long)row * ldc + col] = (half_t)v;
          else        ((float*)Cv)[coff + (long)row * ldc + col] = v;
        }
      }
}

// ---------------------------------------------------------------------------
// Fused attention v2: swapped QK^T (S^T in D-layout: row=key, col=qrow) ->
// in-register softmax (2 shuffles per row-set) -> P^T built by per-lane
// f32->f16 casts feeding 16x16x16 MFMA B-operand (k = g*4+j == D r-run) ->
// OUT^T accumulate -> vectorized 8B stores. No LDS, no barriers.
// Per wave: 32 qrows (fi=2), all 256 compressed keys.
// ---------------------------------------------------------------------------
__global__ __launch_bounds__(256, 2)
void attn_fused(const half_t* __restrict__ q, const half_t* __restrict__ kE,
                const half_t* __restrict__ vFt, half_t* __restrict__ outp, int L)
{
  const int tid = threadIdx.x, w = tid >> 6, lane = tid & 63;
  const int g = lane >> 4, c = lane & 15;
  const int l0 = blockIdx.x * 128, h = blockIdx.y, b = blockIdx.z;

  const half_t* qb  = q + ((long)b * L + l0 + w * 32) * 1024 + h * 64;
  const half_t* keb = kE + (long)b * 262144 + h * 64;              // [key][1024]
  const half_t* vb  = vFt + (long)b * 262144 + (long)h * 64 * 256; // [d][256]
  half_t* ob = outp + ((long)b * L + l0 + w * 32) * 1024 + h * 64;

  // q as B-operand fragments (n = qrow = c, k = d)
  f16x8 qf[2][2];
#pragma unroll
  for (int fi = 0; fi < 2; ++fi)
#pragma unroll
    for (int ks = 0; ks < 2; ++ks)
      qf[fi][ks] = *(const f16x8*)(qb + (long)(fi * 16 + c) * 1024 + ks * 32 + g * 8);

  const f32x4 zero = {0.f, 0.f, 0.f, 0.f};
  f32x4 s[2][16];
#pragma unroll
  for (int fi = 0; fi < 2; ++fi)
#pragma unroll
    for (int fj = 0; fj < 16; ++fj) s[fi][fj] = zero;

  // S^T = kE · q^T : A = kE (m=key, k=d), B = q (n=qrow, k=d)
#pragma unroll
  for (int fj = 0; fj < 16; ++fj) {
    f16x8 k0 = *(const f16x8*)(keb + (long)(fj * 16 + c) * 1024 + g * 8);
    f16x8 k1 = *(const f16x8*)(keb + (long)(fj * 16 + c) * 1024 + 32 + g * 8);
#pragma unroll
    for (int fi = 0; fi < 2; ++fi) {
      s[fi][fj] = __builtin_amdgcn_mfma_f32_16x16x32_f16(k0, qf[fi][0], s[fi][fj], 0, 0, 0);
      s[fi][fj] = __builtin_amdgcn_mfma_f32_16x16x32_f16(k1, qf[fi][1], s[fi][fj], 0, 0, 0);
    }
  }

  // prefetch vFt for kc=0 (independent of softmax)
  f16x4 va0[4];
#pragma unroll
  for (int fd = 0; fd < 4; ++fd)
    va0[fd] = *(const f16x4*)(vb + (long)(fd * 16 + c) * 256 + g * 4);

  // softmax over keys: per fi, each lane holds 64 vals (16 frags x 4 regs) for
  // qrow col c; keys split across 4 lane-groups -> xor16 + xor32 reduce.
  // Then P^T B-fragments: p[fi][kc], elem j = key kc*16 + g*4 + j  (== D r-run).
  f16x4 p[2][16];
#pragma unroll
  for (int fi = 0; fi < 2; ++fi) {
    float m = -3.0e38f;
#pragma unroll
    for (int fj = 0; fj < 16; ++fj)
#pragma unroll
      for (int r = 0; r < 4; ++r) m = fmaxf(m, s[fi][fj][r]);
    m = fmaxf(m, __shfl_xor(m, 16));
    m = fmaxf(m, __shfl_xor(m, 32));
    float sum = 0.f;
#pragma unroll
    for (int fj = 0; fj < 16; ++fj)
#pragma unroll
      for (int r = 0; r < 4; ++r) {
        float e = __expf(s[fi][fj][r] - m);
        s[fi][fj][r] = e; sum += e;
      }
    sum += __shfl_xor(sum, 16);
    sum += __shfl_xor(sum, 32);
    const float inv = 1.0f / sum;
#pragma unroll
    for (int fj = 0; fj < 16; ++fj) {
      f16x4 fr;
#pragma unroll
      for (int r = 0; r < 4; ++r) fr[r] = (half_t)(s[fi][fj][r] * inv);
      p[fi][fj] = fr;
    }
  }

  // OUT^T = vFt · P^T : A = vFt (m=d, k=key), B = P^T (n=qrow, k=key), K=16/mfma
  f32x4 o[2][4];
#pragma unroll
  for (int fi = 0; fi < 2; ++fi)
#pragma unroll
    for (int fd = 0; fd < 4; ++fd) o[fi][fd] = zero;

#pragma unroll
  for (int kc = 0; kc < 16; ++kc) {
    f16x4 va[4];
#pragma unroll
    for (int fd = 0; fd < 4; ++fd)
      va[fd] = (kc == 0) ? va0[fd]
             : *(const f16x4*)(vb + (long)(fd * 16 + c) * 256 + kc * 16 + g * 4);
#pragma unroll
    for (int fi = 0; fi < 2; ++fi)
#pragma unroll
      for (int fd = 0; fd < 4; ++fd)
        o[fi][fd] = __builtin_amdgcn_mfma_f32_16x16x16f16(va[fd], p[fi][kc], o[fi][fd], 0, 0, 0);
  }

  // store OUT^T: row = d = fd*16 + g*4 + r (r contiguous -> 8B), col = qrow
#pragma unroll
  for (int fi = 0; fi < 2; ++fi)
#pragma unroll
    for (int fd = 0; fd < 4; ++fd) {
      f16x4 st;
#pragma unroll
      for (int r = 0; r < 4; ++r) st[r] = (half_t)o[fi][fd][r];
      *(f16x4*)(ob + (long)(fi * 16 + c) * 1024 + fd * 16 + g * 4) = st;
    }
}

// ---------------------------------------------------------------------------
// helpers
// ---------------------------------------------------------------------------
__global__ void cvt_f16(const float* __restrict__ in, half_t* __restrict__ out, long n) {
  long i = ((long)blockIdx.x * 256 + threadIdx.x) * 4;
  if (i >= n) return;
  float4v v = *(const float4v*)(in + i);
  f16x4 o;
#pragma unroll
  for (int j = 0; j < 4; ++j) o[j] = (half_t)v[j];
  *(f16x4*)(out + i) = o;
}

// x [4][4096][1024] f32 -> xhf fp16 (same layout) AND xT [4][1024][4096] fp16
__global__ void xpass(const float* __restrict__ x, half_t* __restrict__ xhf,
                      half_t* __restrict__ xT) {
  __shared__ float t[32][33];
  const int b = blockIdx.z, d0 = blockIdx.x * 32, l0 = blockIdx.y * 32;
  const int tx = threadIdx.x, ty = threadIdx.y;
  const float* ip = x + ((long)b * 4096 + l0) * 1024 + d0;
  half_t* oh = xhf + ((long)b * 4096 + l0) * 1024 + d0;
#pragma unroll
  for (int j = 0; j < 4; ++j) {
    float v = ip[(long)(ty + 8 * j) * 1024 + tx];
    t[ty + 8 * j][tx] = v;
    oh[(long)(ty + 8 * j) * 1024 + tx] = (half_t)v;
  }
  __syncthreads();
  half_t* ot = xT + ((long)b * 1024 + d0) * 4096 + l0;
#pragma unroll
  for (int j = 0; j < 4; ++j)
    ot[(long)(ty + 8 * j) * 4096 + tx] = (half_t)t[tx][ty + 8 * j];
}

// E [4096][256] f32 -> E^T [256][4096] fp16, plus colsum(E) -> ssum[256]
__global__ void efpass(const float* __restrict__ in, half_t* __restrict__ outT,
                       float* __restrict__ ssum) {
  __shared__ float t[32][33];
  __shared__ float ps[8][32];
  const int k0 = blockIdx.x * 32, l0 = blockIdx.y * 32;
  const int tx = threadIdx.x, ty = threadIdx.y;
  float p = 0.f;
#pragma unroll
  for (int j = 0; j < 4; ++j) {
    float v = in[(long)(l0 + ty + 8 * j) * 256 + k0 + tx];
    t[ty + 8 * j][tx] = v; p += v;
  }
  ps[ty][tx] = p;
  __syncthreads();
  if (ty == 0) {
    float a = 0.f;
#pragma unroll
    for (int r = 0; r < 8; ++r) a += ps[r][tx];
    atomicAdd(&ssum[k0 + tx], a);
  }
#pragma unroll
  for (int j = 0; j < 4; ++j)
    outT[(long)(k0 + ty + 8 * j) * 4096 + l0 + tx] = (half_t)t[tx][ty + 8 * j];
}

__global__ void transpose_f32_f16(const float* __restrict__ in, half_t* __restrict__ out,
                                  int R, int C) {
  __shared__ float t[32][33];
  const int cx = blockIdx.x * 32 + threadIdx.x;
  const int r0 = blockIdx.y * 32;
#pragma unroll
  for (int j = 0; j < 4; ++j)
    t[threadIdx.y + 8 * j][threadIdx.x] = in[(long)(r0 + threadIdx.y + 8 * j) * C + cx];
  __syncthreads();
  const int rx = r0 + threadIdx.x;
  const int cy = blockIdx.x * 32 + threadIdx.y;
#pragma unroll
  for (int j = 0; j < 4; ++j)
    out[(long)(cy + 8 * j) * R + rx] = (half_t)t[threadIdx.x][threadIdx.y + 8 * j];
}

// ---------------------------------------------------------------------------
extern "C" void kernel_launch(void* const* d_in, const int* in_sizes, int n_in,
                              void* d_out, int out_size, void* d_ws, size_t ws_size,
                              hipStream_t stream)
{
  const float* x  = (const float*)d_in[0];
  const float* Wq = (const float*)d_in[1];
  const float* bq = (const float*)d_in[2];
  const float* Wk = (const float*)d_in[3];
  const float* bk = (const float*)d_in[4];
  const float* Wv = (const float*)d_in[5];
  const float* bv = (const float*)d_in[6];
  const float* E  = (const float*)d_in[7];
  const float* F  = (const float*)d_in[8];
  const float* Wo = (const float*)d_in[9];
  const float* bo = (const float*)d_in[10];
  float* out = (float*)d_out;

  char* ws = (char*)d_ws;
  half_t* xhf  = (half_t*)(ws);                 // 33.5MB; later reused as out_pre
  half_t* xT   = (half_t*)(ws + 33554432);      // 33.5MB (dead after xEF gemm)
  half_t* qhf  = (half_t*)(ws + 67108864);      // 33.5MB
  half_t* Wqt  = (half_t*)(ws + 100663296);
  half_t* Wkt  = Wqt + 1048576;
  half_t* Wvt  = Wkt + 1048576;
  half_t* Wot  = Wvt + 1048576;
  half_t* EFt  = (half_t*)(ws + 109051904);     // [512][4096]: E^T on top of F^T
  half_t* xEF  = (half_t*)(ws + 113246208);     // per b: [512][1024] = [xE; xF]
  half_t* kEb  = (half_t*)(ws + 117440512);     // per b: [256][1024]
  half_t* vFtb = (half_t*)(ws + 119537664);     // per b: [1024][256]
  float*  sEF  = (float*)(ws + 121634816);      // sE[256], sF[256]
  half_t* outp = xhf;                           // out_pre overlays x_f16
  float*  xEFf = (float*)d_out;                 // 8MB split-K scratch in d_out head
                                                // (fully overwritten by final GEMM)

  hipMemsetAsync(sEF, 0, 2048, stream);
  hipMemsetAsync(xEFf, 0, 8388608, stream);
  dim3 tb(32, 8);
  xpass<<<dim3(32, 128, 4), tb, 0, stream>>>(x, xhf, xT);
  efpass<<<dim3(8, 128, 1), tb, 0, stream>>>(E, EFt, sEF);
  efpass<<<dim3(8, 128, 1), tb, 0, stream>>>(F, EFt + 1048576, sEF + 256);
  transpose_f32_f16<<<dim3(32, 32, 1), tb, 0, stream>>>(Wq, Wqt, 1024, 1024);
  transpose_f32_f16<<<dim3(32, 32, 1), tb, 0, stream>>>(Wk, Wkt, 1024, 1024);
  transpose_f32_f16<<<dim3(32, 32, 1), tb, 0, stream>>>(Wv, Wvt, 1024, 1024);
  transpose_f32_f16<<<dim3(32, 32, 1), tb, 0, stream>>>(Wo, Wot, 1024, 1024);

  // xEFf[b] = [E^T; F^T] @ x_b  (M=512, N=1024, K=4096) split-K=8, f32 atomics
  gemm_bt<128,128,64,64,0,3,8><<<dim3(4, 8, 32), 256, 0, stream>>>(
      EFt, xT, (void*)xEFf, nullptr, nullptr, 512, 1024, 4096, 4096, 4096, 1024, 1.f,
      0, 4194304, 524288);
  cvt_f16<<<2048, 256, 0, stream>>>(xEFf, xEF, 2097152L);

  // q = (x@Wq + bq) * hd^-0.5  -> fp16 [16384][1024]
  gemm_bt<128,128,64,64,1,1,1><<<dim3(128, 8, 1), 256, 0, stream>>>(
      xhf, Wqt, qhf, bq, nullptr, 16384, 1024, 1024, 1024, 1024, 1024, 0.125f, 0, 0, 0);
  // kE[b] = xE_b @ Wk + sE*bk   (M=256, N=1024, K=1024)
  gemm_bt<128,128,64,64,1,2,1><<<dim3(2, 8, 4), 256, 0, stream>>>(
      xEF, Wkt, kEb, bk, sEF, 256, 1024, 1024, 1024, 1024, 1024, 1.f,
      524288, 0, 262144);
  // vFt[b] = Wv^T @ xF_b^T + bv*sF  (M=1024, N=256, K=1024)
  gemm_bt<128,128,64,64,1,2,1><<<dim3(8, 2, 4), 256, 0, stream>>>(
      Wvt, xEF + 262144, vFtb, sEF + 256, bv, 1024, 256, 1024, 1024, 1024, 256, 1.f,
      0, 524288, 262144);
  // fused qk^T -> softmax -> PV   (writes out_pre fp16 [b][l][h*64+d])
  attn_fused<<<dim3(32, 16, 4), 256, 0, stream>>>(qhf, kEb, vFtb, outp, 4096);
  // out = out_pre @ Wo + bo  (fp32)
  gemm_bt<128,128,64,64,0,1,1><<<dim3(128, 8, 1), 256, 0, stream>>>(
      outp, Wot, (void*)out, bo, nullptr, 16384, 1024, 1024, 1024, 1024, 1024, 1.f, 0, 0, 0);
  (void)in_sizes; (void)n_in; (void)out_size; (void)ws_size;
}

// Round 6
// 360.188 us; speedup vs baseline: 1.0043x; 1.0043x over previous
//
#include <hip/hip_runtime.h>

typedef _Float16 half_t;
typedef __attribute__((ext_vector_type(8))) _Float16 f16x8;   // 8 fp16 = 4 VGPRs
typedef __attribute__((ext_vector_type(4))) _Float16 f16x4;
typedef __attribute__((ext_vector_type(4))) float f32x4;
typedef __attribute__((ext_vector_type(4))) float float4v;

__device__ __forceinline__ void gload_lds16(const void* g, void* l) {
  __builtin_amdgcn_global_load_lds(
      (const __attribute__((address_space(1))) void*)g,
      (__attribute__((address_space(3))) void*)l, 16, 0, 0);
}

// ---------------------------------------------------------------------------
// C = A (MxK, row-major fp16) * B (KxN) given Bt = B^T (NxK row-major fp16)
// MODE 0: C = acc ; MODE 1: C = (acc + bias[col]) * alpha
// MODE 2: C = acc + rowscale[row] * bias[col]
// MODE 3: atomicAdd f32 (split-K accumulate), no bias
// SK: split-K factor; blockIdx.z = batch * SK + kslice.
// ---------------------------------------------------------------------------
template<int BM, int BN, int WM, int WN, int OUTF16, int MODE, int SK>
__global__ __launch_bounds__(256, 2)
void gemm_bt(const half_t* __restrict__ A, const half_t* __restrict__ Bt,
             void* __restrict__ Cv, const float* __restrict__ bias,
             const float* __restrict__ rowscale,
             int M, int N, int K, int lda, int ldb, int ldc, float alpha,
             long sA, long sB, long sC)
{
  constexpr int FM = WM / 16, FN = WN / 16, CW = BN / WN;
  __shared__ __attribute__((aligned(16))) half_t As[BM * 32];
  __shared__ __attribute__((aligned(16))) half_t Bs[BN * 32];

  const int tid = threadIdx.x, w = tid >> 6, lane = tid & 63;
  const int wr = w / CW, wc = w % CW;
  const int z = blockIdx.z / SK, ks = blockIdx.z % SK;
  const half_t* Ab = A + (long)z * sA;
  const half_t* Bb = Bt + (long)z * sB;
  const int m0 = blockIdx.x * BM, n0 = blockIdx.y * BN;
  const int g = lane >> 4, cc = lane & 15;
  const int srow = lane >> 2, scol = (lane & 3) * 8;   // staging lane map

  const f32x4 zero = {0.f, 0.f, 0.f, 0.f};
  f32x4 acc[FM][FN];
#pragma unroll
  for (int i = 0; i < FM; ++i)
#pragma unroll
    for (int j = 0; j < FN; ++j) acc[i][j] = zero;

  const int kchunk = K / SK;
  for (int kt = ks * kchunk; kt < (ks + 1) * kchunk; kt += 32) {
#pragma unroll
    for (int j = 0; j < BM / 64; ++j) {
      const int bi = w * (BM / 64) + j;
      gload_lds16(Ab + (long)(m0 + bi * 16 + srow) * lda + kt + scol, &As[bi * 512]);
    }
#pragma unroll
    for (int j = 0; j < BN / 64; ++j) {
      const int bi = w * (BN / 64) + j;
      gload_lds16(Bb + (long)(n0 + bi * 16 + srow) * ldb + kt + scol, &Bs[bi * 512]);
    }
    __syncthreads();   // drains vmcnt -> staged data visible

    f16x8 af[FM], bf[FN];
#pragma unroll
    for (int i = 0; i < FM; ++i)
      af[i] = *(const f16x8*)&As[(wr * WM + i * 16 + cc) * 32 + g * 8];
#pragma unroll
    for (int j = 0; j < FN; ++j)
      bf[j] = *(const f16x8*)&Bs[(wc * WN + j * 16 + cc) * 32 + g * 8];
#pragma unroll
    for (int i = 0; i < FM; ++i)
#pragma unroll
      for (int j = 0; j < FN; ++j)
        acc[i][j] = __builtin_amdgcn_mfma_f32_16x16x32_f16(af[i], bf[j], acc[i][j], 0, 0, 0);
    __syncthreads();   // before next-tile staging overwrites LDS
  }

  const long coff = (long)z * sC;
#pragma unroll
  for (int i = 0; i < FM; ++i)
#pragma unroll
    for (int j = 0; j < FN; ++j)
#pragma unroll
      for (int r = 0; r < 4; ++r) {
        const int row = m0 + wr * WM + i * 16 + g * 4 + r;   // C/D: row=(l>>4)*4+reg
        const int col = n0 + wc * WN + j * 16 + cc;          //      col=l&15
        float v = acc[i][j][r];
        if (MODE == 1) v = (v + bias[col]) * alpha;
        if (MODE == 2) v = v + rowscale[row] * bias[col];
        if (MODE == 3) {
          atomicAdd(&((float*)Cv)[coff + (long)row * ldc + col], v);
        } else {
          if (OUTF16) ((half_t*)Cv)[coff + (long)row * ldc + col] = (half_t)v;
          else        ((float*)Cv)[coff + (long)row * ldc + col] = v;
        }
      }
}

// ---------------------------------------------------------------------------
// Fused attention v3 (flash-chunked): swapped QK^T per 64-key chunk
// (S^T D-layout: row=key, col=qrow), online max/sum with rescale,
// P^T fed straight to 16x16x16 MFMA B-operand (k = g*4+j == D r-run),
// OUT^T accumulate, final 1/l scale, vectorized 8B stores.
// No LDS, no barriers. Per wave: 32 qrows, keys chunked 4x64.
// ---------------------------------------------------------------------------
__global__ __launch_bounds__(256, 3)
void attn_fused(const half_t* __restrict__ q, const half_t* __restrict__ kE,
                const half_t* __restrict__ vFt, half_t* __restrict__ outp, int L)
{
  const int tid = threadIdx.x, w = tid >> 6, lane = tid & 63;
  const int g = lane >> 4, c = lane & 15;
  const int l0 = blockIdx.x * 128, h = blockIdx.y, b = blockIdx.z;

  const half_t* qb  = q + ((long)b * L + l0 + w * 32) * 1024 + h * 64;
  const half_t* keb = kE + (long)b * 262144 + h * 64;              // [key][1024]
  const half_t* vb  = vFt + (long)b * 262144 + (long)h * 64 * 256; // [d][256]
  half_t* ob = outp + ((long)b * L + l0 + w * 32) * 1024 + h * 64;

  // q as B-operand fragments (n = qrow_local = fi*16 + c, k = d)
  f16x8 qf[2][2];
#pragma unroll
  for (int fi = 0; fi < 2; ++fi)
#pragma unroll
    for (int ks = 0; ks < 2; ++ks)
      qf[fi][ks] = *(const f16x8*)(qb + (long)(fi * 16 + c) * 1024 + ks * 32 + g * 8);

  const f32x4 zero = {0.f, 0.f, 0.f, 0.f};
  f32x4 o[2][4];
#pragma unroll
  for (int fi = 0; fi < 2; ++fi)
#pragma unroll
    for (int fd = 0; fd < 4; ++fd) o[fi][fd] = zero;
  float mrun[2] = {-3.0e38f, -3.0e38f};
  float lrun[2] = {0.f, 0.f};

  for (int ch = 0; ch < 4; ++ch) {
    // --- QK^T chunk: S^T = kE · q^T, keys = ch*64 + fj*16 + g*4 + r ---
    f32x4 s[2][4];
#pragma unroll
    for (int fi = 0; fi < 2; ++fi)
#pragma unroll
      for (int fj = 0; fj < 4; ++fj) s[fi][fj] = zero;
#pragma unroll
    for (int fj = 0; fj < 4; ++fj) {
      f16x8 k0 = *(const f16x8*)(keb + (long)(ch * 64 + fj * 16 + c) * 1024 + g * 8);
      f16x8 k1 = *(const f16x8*)(keb + (long)(ch * 64 + fj * 16 + c) * 1024 + 32 + g * 8);
#pragma unroll
      for (int fi = 0; fi < 2; ++fi) {
        s[fi][fj] = __builtin_amdgcn_mfma_f32_16x16x32_f16(k0, qf[fi][0], s[fi][fj], 0, 0, 0);
        s[fi][fj] = __builtin_amdgcn_mfma_f32_16x16x32_f16(k1, qf[fi][1], s[fi][fj], 0, 0, 0);
      }
    }

    // --- online softmax update (per fi, qrow = col c; reduce across g via
    //     shfl16+shfl32; each lane holds 16 of the 64 chunk keys) ---
    f16x4 p[2][4];
#pragma unroll
    for (int fi = 0; fi < 2; ++fi) {
      float cm = -3.0e38f;
#pragma unroll
      for (int fj = 0; fj < 4; ++fj)
#pragma unroll
        for (int r = 0; r < 4; ++r) cm = fmaxf(cm, s[fi][fj][r]);
      cm = fmaxf(cm, __shfl_xor(cm, 16));
      cm = fmaxf(cm, __shfl_xor(cm, 32));
      const float mnew = fmaxf(mrun[fi], cm);
      const float sc = __expf(mrun[fi] - mnew);   // 0 on first chunk
      float csum = 0.f;
#pragma unroll
      for (int fj = 0; fj < 4; ++fj) {
        f16x4 fr;
#pragma unroll
        for (int r = 0; r < 4; ++r) {
          float e = __expf(s[fi][fj][r] - mnew);
          fr[r] = (half_t)e; csum += e;
        }
        p[fi][fj] = fr;
      }
      csum += __shfl_xor(csum, 16);
      csum += __shfl_xor(csum, 32);
      lrun[fi] = lrun[fi] * sc + csum;
      mrun[fi] = mnew;
#pragma unroll
      for (int fd = 0; fd < 4; ++fd)
#pragma unroll
        for (int r = 0; r < 4; ++r) o[fi][fd][r] *= sc;
    }

    // --- PV chunk: OUT^T += vFt · P^T (K=16 per mfma) ---
#pragma unroll
    for (int kc = 0; kc < 4; ++kc) {
      f16x4 va[4];
#pragma unroll
      for (int fd = 0; fd < 4; ++fd)
        va[fd] = *(const f16x4*)(vb + (long)(fd * 16 + c) * 256 + ch * 64 + kc * 16 + g * 4);
#pragma unroll
      for (int fi = 0; fi < 2; ++fi)
#pragma unroll
        for (int fd = 0; fd < 4; ++fd)
          o[fi][fd] = __builtin_amdgcn_mfma_f32_16x16x16f16(va[fd], p[fi][kc], o[fi][fd], 0, 0, 0);
    }
  }

  // store OUT^T * 1/l: row = d = fd*16 + g*4 + r (contiguous -> 8B), col = qrow
#pragma unroll
  for (int fi = 0; fi < 2; ++fi) {
    const float inv = 1.0f / lrun[fi];
#pragma unroll
    for (int fd = 0; fd < 4; ++fd) {
      f16x4 st;
#pragma unroll
      for (int r = 0; r < 4; ++r) st[r] = (half_t)(o[fi][fd][r] * inv);
      *(f16x4*)(ob + (long)(fi * 16 + c) * 1024 + fd * 16 + g * 4) = st;
    }
  }
}

// ---------------------------------------------------------------------------
// helpers
// ---------------------------------------------------------------------------
__global__ void cvt_f16(const float* __restrict__ in, half_t* __restrict__ out, long n) {
  long i = ((long)blockIdx.x * 256 + threadIdx.x) * 4;
  if (i >= n) return;
  float4v v = *(const float4v*)(in + i);
  f16x4 o;
#pragma unroll
  for (int j = 0; j < 4; ++j) o[j] = (half_t)v[j];
  *(f16x4*)(out + i) = o;
}

// x [4][4096][1024] f32 -> xhf fp16 (same layout) AND xT [4][1024][4096] fp16
__global__ void xpass(const float* __restrict__ x, half_t* __restrict__ xhf,
                      half_t* __restrict__ xT) {
  __shared__ float t[32][33];
  const int b = blockIdx.z, d0 = blockIdx.x * 32, l0 = blockIdx.y * 32;
  const int tx = threadIdx.x, ty = threadIdx.y;
  const float* ip = x + ((long)b * 4096 + l0) * 1024 + d0;
  half_t* oh = xhf + ((long)b * 4096 + l0) * 1024 + d0;
#pragma unroll
  for (int j = 0; j < 4; ++j) {
    float v = ip[(long)(ty + 8 * j) * 1024 + tx];
    t[ty + 8 * j][tx] = v;
    oh[(long)(ty + 8 * j) * 1024 + tx] = (half_t)v;
  }
  __syncthreads();
  half_t* ot = xT + ((long)b * 1024 + d0) * 4096 + l0;
#pragma unroll
  for (int j = 0; j < 4; ++j)
    ot[(long)(ty + 8 * j) * 4096 + tx] = (half_t)t[tx][ty + 8 * j];
}

// E [4096][256] f32 -> E^T [256][4096] fp16, plus colsum(E) -> ssum[256]
__global__ void efpass(const float* __restrict__ in, half_t* __restrict__ outT,
                       float* __restrict__ ssum) {
  __shared__ float t[32][33];
  __shared__ float ps[8][32];
  const int k0 = blockIdx.x * 32, l0 = blockIdx.y * 32;
  const int tx = threadIdx.x, ty = threadIdx.y;
  float p = 0.f;
#pragma unroll
  for (int j = 0; j < 4; ++j) {
    float v = in[(long)(l0 + ty + 8 * j) * 256 + k0 + tx];
    t[ty + 8 * j][tx] = v; p += v;
  }
  ps[ty][tx] = p;
  __syncthreads();
  if (ty == 0) {
    float a = 0.f;
#pragma unroll
    for (int r = 0; r < 8; ++r) a += ps[r][tx];
    atomicAdd(&ssum[k0 + tx], a);
  }
#pragma unroll
  for (int j = 0; j < 4; ++j)
    outT[(long)(k0 + ty + 8 * j) * 4096 + l0 + tx] = (half_t)t[tx][ty + 8 * j];
}

__global__ void transpose_f32_f16(const float* __restrict__ in, half_t* __restrict__ out,
                                  int R, int C) {
  __shared__ float t[32][33];
  const int cx = blockIdx.x * 32 + threadIdx.x;
  const int r0 = blockIdx.y * 32;
#pragma unroll
  for (int j = 0; j < 4; ++j)
    t[threadIdx.y + 8 * j][threadIdx.x] = in[(long)(r0 + threadIdx.y + 8 * j) * C + cx];
  __syncthreads();
  const int rx = r0 + threadIdx.x;
  const int cy = blockIdx.x * 32 + threadIdx.y;
#pragma unroll
  for (int j = 0; j < 4; ++j)
    out[(long)(cy + 8 * j) * R + rx] = (half_t)t[threadIdx.x][threadIdx.y + 8 * j];
}

// ---------------------------------------------------------------------------
extern "C" void kernel_launch(void* const* d_in, const int* in_sizes, int n_in,
                              void* d_out, int out_size, void* d_ws, size_t ws_size,
                              hipStream_t stream)
{
  const float* x  = (const float*)d_in[0];
  const float* Wq = (const float*)d_in[1];
  const float* bq = (const float*)d_in[2];
  const float* Wk = (const float*)d_in[3];
  const float* bk = (const float*)d_in[4];
  const float* Wv = (const float*)d_in[5];
  const float* bv = (const float*)d_in[6];
  const float* E  = (const float*)d_in[7];
  const float* F  = (const float*)d_in[8];
  const float* Wo = (const float*)d_in[9];
  const float* bo = (const float*)d_in[10];
  float* out = (float*)d_out;

  char* ws = (char*)d_ws;
  half_t* xhf  = (half_t*)(ws);                 // 33.5MB; later reused as out_pre
  half_t* xT   = (half_t*)(ws + 33554432);      // 33.5MB (dead after xEF gemm)
  half_t* qhf  = (half_t*)(ws + 67108864);      // 33.5MB
  half_t* Wqt  = (half_t*)(ws + 100663296);
  half_t* Wkt  = Wqt + 1048576;
  half_t* Wvt  = Wkt + 1048576;
  half_t* Wot  = Wvt + 1048576;
  half_t* EFt  = (half_t*)(ws + 109051904);     // [512][4096]: E^T on top of F^T
  half_t* xEF  = (half_t*)(ws + 113246208);     // per b: [512][1024] = [xE; xF]
  half_t* kEb  = (half_t*)(ws + 117440512);     // per b: [256][1024]
  half_t* vFtb = (half_t*)(ws + 119537664);     // per b: [1024][256]
  float*  sEF  = (float*)(ws + 121634816);      // sE[256], sF[256]
  half_t* outp = xhf;                           // out_pre overlays x_f16
  float*  xEFf = (float*)d_out;                 // 8MB split-K scratch in d_out head
                                                // (fully overwritten by final GEMM)

  hipMemsetAsync(sEF, 0, 2048, stream);
  hipMemsetAsync(xEFf, 0, 8388608, stream);
  dim3 tb(32, 8);
  xpass<<<dim3(32, 128, 4), tb, 0, stream>>>(x, xhf, xT);
  efpass<<<dim3(8, 128, 1), tb, 0, stream>>>(E, EFt, sEF);
  efpass<<<dim3(8, 128, 1), tb, 0, stream>>>(F, EFt + 1048576, sEF + 256);
  transpose_f32_f16<<<dim3(32, 32, 1), tb, 0, stream>>>(Wq, Wqt, 1024, 1024);
  transpose_f32_f16<<<dim3(32, 32, 1), tb, 0, stream>>>(Wk, Wkt, 1024, 1024);
  transpose_f32_f16<<<dim3(32, 32, 1), tb, 0, stream>>>(Wv, Wvt, 1024, 1024);
  transpose_f32_f16<<<dim3(32, 32, 1), tb, 0, stream>>>(Wo, Wot, 1024, 1024);

  // xEFf[b] = [E^T; F^T] @ x_b  (M=512, N=1024, K=4096) split-K=8, f32 atomics
  gemm_bt<128,128,64,64,0,3,8><<<dim3(4, 8, 32), 256, 0, stream>>>(
      EFt, xT, (void*)xEFf, nullptr, nullptr, 512, 1024, 4096, 4096, 4096, 1024, 1.f,
      0, 4194304, 524288);
  cvt_f16<<<2048, 256, 0, stream>>>(xEFf, xEF, 2097152L);

  // q = (x@Wq + bq) * hd^-0.5  -> fp16 [16384][1024]
  gemm_bt<128,128,64,64,1,1,1><<<dim3(128, 8, 1), 256, 0, stream>>>(
      xhf, Wqt, qhf, bq, nullptr, 16384, 1024, 1024, 1024, 1024, 1024, 0.125f, 0, 0, 0);
  // kE[b] = xE_b @ Wk + sE*bk   (M=256, N=1024, K=1024)
  gemm_bt<128,128,64,64,1,2,1><<<dim3(2, 8, 4), 256, 0, stream>>>(
      xEF, Wkt, kEb, bk, sEF, 256, 1024, 1024, 1024, 1024, 1024, 1.f,
      524288, 0, 262144);
  // vFt[b] = Wv^T @ xF_b^T + bv*sF  (M=1024, N=256, K=1024)
  gemm_bt<128,128,64,64,1,2,1><<<dim3(8, 2, 4), 256, 0, stream>>>(
      Wvt, xEF + 262144, vFtb, sEF + 256, bv, 1024, 256, 1024, 1024, 1024, 256, 1.f,
      0, 524288, 262144);
  // fused qk^T -> softmax -> PV   (writes out_pre fp16 [b][l][h*64+d])
  attn_fused<<<dim3(32, 16, 4), 256, 0, stream>>>(qhf, kEb, vFtb, outp, 4096);
  // out = out_pre @ Wo + bo  (fp32)
  gemm_bt<128,128,64,64,0,1,1><<<dim3(128, 8, 1), 256, 0, stream>>>(
      outp, Wot, (void*)out, bo, nullptr, 16384, 1024, 1024, 1024, 1024, 1024, 1.f, 0, 0, 0);
  (void)in_sizes; (void)n_in; (void)out_size; (void)ws_size;
}

// Round 7
// 300.079 us; speedup vs baseline: 1.2054x; 1.2003x over previous
//
#include <hip/hip_runtime.h>

typedef _Float16 half_t;
typedef __attribute__((ext_vector_type(8))) _Float16 f16x8;   // 8 fp16 = 4 VGPRs
typedef __attribute__((ext_vector_type(4))) _Float16 f16x4;
typedef __attribute__((ext_vector_type(4))) float f32x4;
typedef __attribute__((ext_vector_type(4))) float float4v;

__device__ __forceinline__ void gload_lds16(const void* g, void* l) {
  __builtin_amdgcn_global_load_lds(
      (const __attribute__((address_space(1))) void*)g,
      (__attribute__((address_space(3))) void*)l, 16, 0, 0);
}

// ---------------------------------------------------------------------------
// C = A (MxK, row-major fp16) * B (KxN) given Bt = B^T (NxK row-major fp16)
// MODE 0: C = acc ; MODE 1: C = (acc + bias[col]) * alpha
// MODE 2: C = acc + rowscale[row] * bias[col]
// MODE 3: atomicAdd f32 (split-K accumulate), no bias
// MODE 4: MODE2 value, stored head-blocked: [col/64][row][col&63] (fp16)
// SK: split-K factor; blockIdx.z = batch * SK + kslice.
// ---------------------------------------------------------------------------
template<int BM, int BN, int WM, int WN, int OUTF16, int MODE, int SK>
__global__ __launch_bounds__(256, 2)
void gemm_bt(const half_t* __restrict__ A, const half_t* __restrict__ Bt,
             void* __restrict__ Cv, const float* __restrict__ bias,
             const float* __restrict__ rowscale,
             int M, int N, int K, int lda, int ldb, int ldc, float alpha,
             long sA, long sB, long sC)
{
  constexpr int FM = WM / 16, FN = WN / 16, CW = BN / WN;
  __shared__ __attribute__((aligned(16))) half_t As[BM * 32];
  __shared__ __attribute__((aligned(16))) half_t Bs[BN * 32];

  const int tid = threadIdx.x, w = tid >> 6, lane = tid & 63;
  const int wr = w / CW, wc = w % CW;
  const int z = blockIdx.z / SK, ks = blockIdx.z % SK;
  const half_t* Ab = A + (long)z * sA;
  const half_t* Bb = Bt + (long)z * sB;
  const int m0 = blockIdx.x * BM, n0 = blockIdx.y * BN;
  const int g = lane >> 4, cc = lane & 15;
  const int srow = lane >> 2, scol = (lane & 3) * 8;   // staging lane map

  const f32x4 zero = {0.f, 0.f, 0.f, 0.f};
  f32x4 acc[FM][FN];
#pragma unroll
  for (int i = 0; i < FM; ++i)
#pragma unroll
    for (int j = 0; j < FN; ++j) acc[i][j] = zero;

  const int kchunk = K / SK;
  for (int kt = ks * kchunk; kt < (ks + 1) * kchunk; kt += 32) {
#pragma unroll
    for (int j = 0; j < BM / 64; ++j) {
      const int bi = w * (BM / 64) + j;
      gload_lds16(Ab + (long)(m0 + bi * 16 + srow) * lda + kt + scol, &As[bi * 512]);
    }
#pragma unroll
    for (int j = 0; j < BN / 64; ++j) {
      const int bi = w * (BN / 64) + j;
      gload_lds16(Bb + (long)(n0 + bi * 16 + srow) * ldb + kt + scol, &Bs[bi * 512]);
    }
    __syncthreads();   // drains vmcnt -> staged data visible

    f16x8 af[FM], bf[FN];
#pragma unroll
    for (int i = 0; i < FM; ++i)
      af[i] = *(const f16x8*)&As[(wr * WM + i * 16 + cc) * 32 + g * 8];
#pragma unroll
    for (int j = 0; j < FN; ++j)
      bf[j] = *(const f16x8*)&Bs[(wc * WN + j * 16 + cc) * 32 + g * 8];
#pragma unroll
    for (int i = 0; i < FM; ++i)
#pragma unroll
      for (int j = 0; j < FN; ++j)
        acc[i][j] = __builtin_amdgcn_mfma_f32_16x16x32_f16(af[i], bf[j], acc[i][j], 0, 0, 0);
    __syncthreads();   // before next-tile staging overwrites LDS
  }

  const long coff = (long)z * sC;
#pragma unroll
  for (int i = 0; i < FM; ++i)
#pragma unroll
    for (int j = 0; j < FN; ++j)
#pragma unroll
      for (int r = 0; r < 4; ++r) {
        const int row = m0 + wr * WM + i * 16 + g * 4 + r;   // C/D: row=(l>>4)*4+reg
        const int col = n0 + wc * WN + j * 16 + cc;          //      col=l&15
        float v = acc[i][j][r];
        if (MODE == 1) v = (v + bias[col]) * alpha;
        if (MODE == 2 || MODE == 4) v = v + rowscale[row] * bias[col];
        if (MODE == 3) {
          atomicAdd(&((float*)Cv)[coff + (long)row * ldc + col], v);
        } else if (MODE == 4) {
          ((half_t*)Cv)[coff + (long)(col >> 6) * ((long)M * 64) + (long)row * 64 + (col & 63)]
              = (half_t)v;
        } else {
          if (OUTF16) ((half_t*)Cv)[coff + (long)row * ldc + col] = (half_t)v;
          else        ((float*)Cv)[coff + (long)row * ldc + col] = v;
        }
      }
}

// ---------------------------------------------------------------------------
// Fused attention v4: LDS-staged K/V per (b,h) block (swizzled, coalesced
// global_load_lds), flash-chunked swapped QK^T -> online softmax -> PV.
// kE head-blocked [b][h][256][64]; vFt [b][h][64][256] (head-contiguous).
// 512 threads (8 waves x 32 qrows = 256 qrows/block). One barrier total.
// ---------------------------------------------------------------------------
__global__ __launch_bounds__(512, 2)
void attn_fused(const half_t* __restrict__ q, const half_t* __restrict__ kEh,
                const half_t* __restrict__ vFt, half_t* __restrict__ outp, int L)
{
  __shared__ __attribute__((aligned(16))) half_t Ks[256 * 64];  // 32KB
  __shared__ __attribute__((aligned(16))) half_t Vs[64 * 256];  // 32KB
  const int tid = threadIdx.x, w = tid >> 6, lane = tid & 63;
  const int g = lane >> 4, c = lane & 15;
  const int l0 = blockIdx.x * 256, h = blockIdx.y, b = blockIdx.z;

  const half_t* keh = kEh + (long)(b * 16 + h) * 16384;   // [256][64]
  const half_t* vfh = vFt + (long)b * 262144 + (long)h * 16384;  // [64][256]
  const half_t* qb  = q + ((long)b * L + l0 + w * 32) * 1024 + h * 64;
  half_t* ob = outp + ((long)b * L + l0 + w * 32) * 1024 + h * 64;

  // stage kE: linear LDS dest, inverse-swizzled source (16B slots, xor row&7)
#pragma unroll
  for (int i = 0; i < 4; ++i) {
    const int row = i * 64 + (tid >> 3), slot = tid & 7;
    gload_lds16(keh + row * 64 + ((slot ^ (row & 7)) << 3),
                (char*)Ks + i * 8192 + tid * 16);
  }
  // stage vFt: rows of 512B = 32 slots of 16B, same xor on low 3 slot bits
#pragma unroll
  for (int i = 0; i < 4; ++i) {
    const int row = i * 16 + (tid >> 5), slot = tid & 31;
    gload_lds16(vfh + row * 256 + ((slot ^ (row & 7)) << 3),
                (char*)Vs + i * 8192 + tid * 16);
  }

  // q as B-operand fragments (n = qrow_local = fi*16 + c, k = d) — global read
  f16x8 qf[2][2];
#pragma unroll
  for (int fi = 0; fi < 2; ++fi)
#pragma unroll
    for (int ks = 0; ks < 2; ++ks)
      qf[fi][ks] = *(const f16x8*)(qb + (long)(fi * 16 + c) * 1024 + ks * 32 + g * 8);

  __syncthreads();   // staged K/V visible

  const f32x4 zero = {0.f, 0.f, 0.f, 0.f};
  f32x4 o[2][4];
#pragma unroll
  for (int fi = 0; fi < 2; ++fi)
#pragma unroll
    for (int fd = 0; fd < 4; ++fd) o[fi][fd] = zero;
  float mrun[2] = {-3.0e38f, -3.0e38f};
  float lrun[2] = {0.f, 0.f};

  for (int ch = 0; ch < 4; ++ch) {
    // --- QK^T chunk from LDS: S^T = kE · q^T, keys = ch*64 + fj*16 + g*4 + r
    f32x4 s[2][4];
#pragma unroll
    for (int fi = 0; fi < 2; ++fi)
#pragma unroll
      for (int fj = 0; fj < 4; ++fj) s[fi][fj] = zero;
#pragma unroll
    for (int fj = 0; fj < 4; ++fj) {
      const int krow = ch * 64 + fj * 16 + c;
      const char* kb = (const char*)Ks + krow * 128;
      f16x8 k0 = *(const f16x8*)(kb + ((g ^ (c & 7)) << 4));
      f16x8 k1 = *(const f16x8*)(kb + (((4 + g) ^ (c & 7)) << 4));
#pragma unroll
      for (int fi = 0; fi < 2; ++fi) {
        s[fi][fj] = __builtin_amdgcn_mfma_f32_16x16x32_f16(k0, qf[fi][0], s[fi][fj], 0, 0, 0);
        s[fi][fj] = __builtin_amdgcn_mfma_f32_16x16x32_f16(k1, qf[fi][1], s[fi][fj], 0, 0, 0);
      }
    }

    // --- online softmax update (per fi; qrow = col c; reduce across g) ---
    f16x4 p[2][4];
#pragma unroll
    for (int fi = 0; fi < 2; ++fi) {
      float cm = -3.0e38f;
#pragma unroll
      for (int fj = 0; fj < 4; ++fj)
#pragma unroll
        for (int r = 0; r < 4; ++r) cm = fmaxf(cm, s[fi][fj][r]);
      cm = fmaxf(cm, __shfl_xor(cm, 16));
      cm = fmaxf(cm, __shfl_xor(cm, 32));
      const float mnew = fmaxf(mrun[fi], cm);
      const float sc = __expf(mrun[fi] - mnew);   // 0 on first chunk
      float csum = 0.f;
#pragma unroll
      for (int fj = 0; fj < 4; ++fj) {
        f16x4 fr;
#pragma unroll
        for (int r = 0; r < 4; ++r) {
          float e = __expf(s[fi][fj][r] - mnew);
          fr[r] = (half_t)e; csum += e;
        }
        p[fi][fj] = fr;
      }
      csum += __shfl_xor(csum, 16);
      csum += __shfl_xor(csum, 32);
      lrun[fi] = lrun[fi] * sc + csum;
      mrun[fi] = mnew;
#pragma unroll
      for (int fd = 0; fd < 4; ++fd)
#pragma unroll
        for (int r = 0; r < 4; ++r) o[fi][fd][r] *= sc;
    }

    // --- PV chunk from LDS: OUT^T += vFt · P^T (K=16 per mfma) ---
#pragma unroll
    for (int kc = 0; kc < 4; ++kc) {
      const int s16 = ch * 8 + kc * 2 + (g >> 1);
      f16x4 va[4];
#pragma unroll
      for (int fd = 0; fd < 4; ++fd) {
        const int drow = fd * 16 + c;
        va[fd] = *(const f16x4*)((const char*)Vs + drow * 512 +
                                 ((s16 ^ (c & 7)) << 4) + (g & 1) * 8);
      }
#pragma unroll
      for (int fi = 0; fi < 2; ++fi)
#pragma unroll
        for (int fd = 0; fd < 4; ++fd)
          o[fi][fd] = __builtin_amdgcn_mfma_f32_16x16x16f16(va[fd], p[fi][kc], o[fi][fd], 0, 0, 0);
    }
  }

  // store OUT^T * 1/l: row = d = fd*16 + g*4 + r (contiguous -> 8B), col = qrow
#pragma unroll
  for (int fi = 0; fi < 2; ++fi) {
    const float inv = 1.0f / lrun[fi];
#pragma unroll
    for (int fd = 0; fd < 4; ++fd) {
      f16x4 st;
#pragma unroll
      for (int r = 0; r < 4; ++r) st[r] = (half_t)(o[fi][fd][r] * inv);
      *(f16x4*)(ob + (long)(fi * 16 + c) * 1024 + fd * 16 + g * 4) = st;
    }
  }
}

// ---------------------------------------------------------------------------
// helpers
// ---------------------------------------------------------------------------
__global__ void cvt_f16(const float* __restrict__ in, half_t* __restrict__ out, long n) {
  long i = ((long)blockIdx.x * 256 + threadIdx.x) * 4;
  if (i >= n) return;
  float4v v = *(const float4v*)(in + i);
  f16x4 o;
#pragma unroll
  for (int j = 0; j < 4; ++j) o[j] = (half_t)v[j];
  *(f16x4*)(out + i) = o;
}

// x [4][4096][1024] f32 -> xhf fp16 (same layout) AND xT [4][1024][4096] fp16
__global__ void xpass(const float* __restrict__ x, half_t* __restrict__ xhf,
                      half_t* __restrict__ xT) {
  __shared__ float t[32][33];
  const int b = blockIdx.z, d0 = blockIdx.x * 32, l0 = blockIdx.y * 32;
  const int tx = threadIdx.x, ty = threadIdx.y;
  const float* ip = x + ((long)b * 4096 + l0) * 1024 + d0;
  half_t* oh = xhf + ((long)b * 4096 + l0) * 1024 + d0;
#pragma unroll
  for (int j = 0; j < 4; ++j) {
    float v = ip[(long)(ty + 8 * j) * 1024 + tx];
    t[ty + 8 * j][tx] = v;
    oh[(long)(ty + 8 * j) * 1024 + tx] = (half_t)v;
  }
  __syncthreads();
  half_t* ot = xT + ((long)b * 1024 + d0) * 4096 + l0;
#pragma unroll
  for (int j = 0; j < 4; ++j)
    ot[(long)(ty + 8 * j) * 4096 + tx] = (half_t)t[tx][ty + 8 * j];
}

// E [4096][256] f32 -> E^T [256][4096] fp16, plus colsum(E) -> ssum[256]
__global__ void efpass(const float* __restrict__ in, half_t* __restrict__ outT,
                       float* __restrict__ ssum) {
  __shared__ float t[32][33];
  __shared__ float ps[8][32];
  const int k0 = blockIdx.x * 32, l0 = blockIdx.y * 32;
  const int tx = threadIdx.x, ty = threadIdx.y;
  float p = 0.f;
#pragma unroll
  for (int j = 0; j < 4; ++j) {
    float v = in[(long)(l0 + ty + 8 * j) * 256 + k0 + tx];
    t[ty + 8 * j][tx] = v; p += v;
  }
  ps[ty][tx] = p;
  __syncthreads();
  if (ty == 0) {
    float a = 0.f;
#pragma unroll
    for (int r = 0; r < 8; ++r) a += ps[r][tx];
    atomicAdd(&ssum[k0 + tx], a);
  }
#pragma unroll
  for (int j = 0; j < 4; ++j)
    outT[(long)(k0 + ty + 8 * j) * 4096 + l0 + tx] = (half_t)t[tx][ty + 8 * j];
}

__global__ void transpose_f32_f16(const float* __restrict__ in, half_t* __restrict__ out,
                                  int R, int C) {
  __shared__ float t[32][33];
  const int cx = blockIdx.x * 32 + threadIdx.x;
  const int r0 = blockIdx.y * 32;
#pragma unroll
  for (int j = 0; j < 4; ++j)
    t[threadIdx.y + 8 * j][threadIdx.x] = in[(long)(r0 + threadIdx.y + 8 * j) * C + cx];
  __syncthreads();
  const int rx = r0 + threadIdx.x;
  const int cy = blockIdx.x * 32 + threadIdx.y;
#pragma unroll
  for (int j = 0; j < 4; ++j)
    out[(long)(cy + 8 * j) * R + rx] = (half_t)t[threadIdx.x][threadIdx.y + 8 * j];
}

// ---------------------------------------------------------------------------
extern "C" void kernel_launch(void* const* d_in, const int* in_sizes, int n_in,
                              void* d_out, int out_size, void* d_ws, size_t ws_size,
                              hipStream_t stream)
{
  const float* x  = (const float*)d_in[0];
  const float* Wq = (const float*)d_in[1];
  const float* bq = (const float*)d_in[2];
  const float* Wk = (const float*)d_in[3];
  const float* bk = (const float*)d_in[4];
  const float* Wv = (const float*)d_in[5];
  const float* bv = (const float*)d_in[6];
  const float* E  = (const float*)d_in[7];
  const float* F  = (const float*)d_in[8];
  const float* Wo = (const float*)d_in[9];
  const float* bo = (const float*)d_in[10];
  float* out = (float*)d_out;

  char* ws = (char*)d_ws;
  half_t* xhf  = (half_t*)(ws);                 // 33.5MB; later reused as out_pre
  half_t* xT   = (half_t*)(ws + 33554432);      // 33.5MB (dead after xEF gemm)
  half_t* qhf  = (half_t*)(ws + 67108864);      // 33.5MB
  half_t* Wqt  = (half_t*)(ws + 100663296);
  half_t* Wkt  = Wqt + 1048576;
  half_t* Wvt  = Wkt + 1048576;
  half_t* Wot  = Wvt + 1048576;
  half_t* EFt  = (half_t*)(ws + 109051904);     // [512][4096]: E^T on top of F^T
  half_t* xEF  = (half_t*)(ws + 113246208);     // per b: [512][1024] = [xE; xF]
  half_t* kEb  = (half_t*)(ws + 117440512);     // per b: [16][256][64] head-blocked
  half_t* vFtb = (half_t*)(ws + 119537664);     // per b: [1024][256] (= [16][64][256])
  float*  sEF  = (float*)(ws + 121634816);      // sE[256], sF[256]
  half_t* outp = xhf;                           // out_pre overlays x_f16
  float*  xEFf = (float*)d_out;                 // 8MB split-K scratch in d_out head
                                                // (fully overwritten by final GEMM)

  hipMemsetAsync(sEF, 0, 2048, stream);
  hipMemsetAsync(xEFf, 0, 8388608, stream);
  dim3 tb(32, 8);
  xpass<<<dim3(32, 128, 4), tb, 0, stream>>>(x, xhf, xT);
  efpass<<<dim3(8, 128, 1), tb, 0, stream>>>(E, EFt, sEF);
  efpass<<<dim3(8, 128, 1), tb, 0, stream>>>(F, EFt + 1048576, sEF + 256);
  transpose_f32_f16<<<dim3(32, 32, 1), tb, 0, stream>>>(Wq, Wqt, 1024, 1024);
  transpose_f32_f16<<<dim3(32, 32, 1), tb, 0, stream>>>(Wk, Wkt, 1024, 1024);
  transpose_f32_f16<<<dim3(32, 32, 1), tb, 0, stream>>>(Wv, Wvt, 1024, 1024);
  transpose_f32_f16<<<dim3(32, 32, 1), tb, 0, stream>>>(Wo, Wot, 1024, 1024);

  // xEFf[b] = [E^T; F^T] @ x_b  (M=512, N=1024, K=4096) split-K=8, f32 atomics
  gemm_bt<128,128,64,64,0,3,8><<<dim3(4, 8, 32), 256, 0, stream>>>(
      EFt, xT, (void*)xEFf, nullptr, nullptr, 512, 1024, 4096, 4096, 4096, 1024, 1.f,
      0, 4194304, 524288);
  cvt_f16<<<2048, 256, 0, stream>>>(xEFf, xEF, 2097152L);

  // q = (x@Wq + bq) * hd^-0.5  -> fp16 [16384][1024]
  gemm_bt<128,128,64,64,1,1,1><<<dim3(128, 8, 1), 256, 0, stream>>>(
      xhf, Wqt, qhf, bq, nullptr, 16384, 1024, 1024, 1024, 1024, 1024, 0.125f, 0, 0, 0);
  // kE[b] = xE_b @ Wk + sE*bk  -> head-blocked [b][16][256][64]  (MODE 4)
  gemm_bt<128,128,64,64,1,4,1><<<dim3(2, 8, 4), 256, 0, stream>>>(
      xEF, Wkt, kEb, bk, sEF, 256, 1024, 1024, 1024, 1024, 1024, 1.f,
      524288, 0, 262144);
  // vFt[b] = Wv^T @ xF_b^T + bv*sF  (M=1024, N=256, K=1024) -> [b][16][64][256]
  gemm_bt<128,128,64,64,1,2,1><<<dim3(8, 2, 4), 256, 0, stream>>>(
      Wvt, xEF + 262144, vFtb, sEF + 256, bv, 1024, 256, 1024, 1024, 1024, 256, 1.f,
      0, 524288, 262144);
  // fused qk^T -> softmax -> PV   (writes out_pre fp16 [b][l][h*64+d])
  attn_fused<<<dim3(16, 16, 4), 512, 0, stream>>>(qhf, kEb, vFtb, outp, 4096);
  // out = out_pre @ Wo + bo  (fp32)
  gemm_bt<128,128,64,64,0,1,1><<<dim3(128, 8, 1), 256, 0, stream>>>(
      outp, Wot, (void*)out, bo, nullptr, 16384, 1024, 1024, 1024, 1024, 1024, 1.f, 0, 0, 0);
  (void)in_sizes; (void)n_in; (void)out_size; (void)ws_size;
}

// Round 8
// 267.085 us; speedup vs baseline: 1.3544x; 1.1235x over previous
//
#include <hip/hip_runtime.h>

typedef _Float16 half_t;
typedef __attribute__((ext_vector_type(8))) _Float16 f16x8;   // 8 fp16 = 4 VGPRs
typedef __attribute__((ext_vector_type(4))) _Float16 f16x4;
typedef __attribute__((ext_vector_type(4))) float f32x4;
typedef __attribute__((ext_vector_type(4))) float float4v;

__device__ __forceinline__ void gload_lds16(const void* g, void* l) {
  __builtin_amdgcn_global_load_lds(
      (const __attribute__((address_space(1))) void*)g,
      (__attribute__((address_space(3))) void*)l, 16, 0, 0);
}

// ---------------------------------------------------------------------------
// C = A (MxK, row-major fp16) * B (KxN) given Bt = B^T (NxK row-major fp16)
// MODE 0: C = acc ; MODE 1: C = (acc + bias[col]) * alpha
// MODE 2: C = acc + rowscale[row] * bias[col]
// MODE 3: split-K partials, plain f32 stores to slice ks: Cv[(ks*NB+z)*sC + ...]
// MODE 4: MODE2 value, stored head-blocked: [col/64][row][col&63] (fp16)
// SK: split-K factor; blockIdx.z = batch * SK + kslice.
// ---------------------------------------------------------------------------
template<int BM, int BN, int WM, int WN, int OUTF16, int MODE, int SK>
__global__ __launch_bounds__(256, 2)
void gemm_bt(const half_t* __restrict__ A, const half_t* __restrict__ Bt,
             void* __restrict__ Cv, const float* __restrict__ bias,
             const float* __restrict__ rowscale,
             int M, int N, int K, int lda, int ldb, int ldc, float alpha,
             long sA, long sB, long sC)
{
  constexpr int FM = WM / 16, FN = WN / 16, CW = BN / WN;
  __shared__ __attribute__((aligned(16))) half_t As[BM * 32];
  __shared__ __attribute__((aligned(16))) half_t Bs[BN * 32];

  const int tid = threadIdx.x, w = tid >> 6, lane = tid & 63;
  const int wr = w / CW, wc = w % CW;
  const int z = blockIdx.z / SK, ks = blockIdx.z % SK;
  const half_t* Ab = A + (long)z * sA;
  const half_t* Bb = Bt + (long)z * sB;
  const int m0 = blockIdx.x * BM, n0 = blockIdx.y * BN;
  const int g = lane >> 4, cc = lane & 15;
  const int srow = lane >> 2, scol = (lane & 3) * 8;   // staging lane map

  const f32x4 zero = {0.f, 0.f, 0.f, 0.f};
  f32x4 acc[FM][FN];
#pragma unroll
  for (int i = 0; i < FM; ++i)
#pragma unroll
    for (int j = 0; j < FN; ++j) acc[i][j] = zero;

  const int kchunk = K / SK;
  for (int kt = ks * kchunk; kt < (ks + 1) * kchunk; kt += 32) {
#pragma unroll
    for (int j = 0; j < BM / 64; ++j) {
      const int bi = w * (BM / 64) + j;
      gload_lds16(Ab + (long)(m0 + bi * 16 + srow) * lda + kt + scol, &As[bi * 512]);
    }
#pragma unroll
    for (int j = 0; j < BN / 64; ++j) {
      const int bi = w * (BN / 64) + j;
      gload_lds16(Bb + (long)(n0 + bi * 16 + srow) * ldb + kt + scol, &Bs[bi * 512]);
    }
    __syncthreads();   // drains vmcnt -> staged data visible

    f16x8 af[FM], bf[FN];
#pragma unroll
    for (int i = 0; i < FM; ++i)
      af[i] = *(const f16x8*)&As[(wr * WM + i * 16 + cc) * 32 + g * 8];
#pragma unroll
    for (int j = 0; j < FN; ++j)
      bf[j] = *(const f16x8*)&Bs[(wc * WN + j * 16 + cc) * 32 + g * 8];
#pragma unroll
    for (int i = 0; i < FM; ++i)
#pragma unroll
      for (int j = 0; j < FN; ++j)
        acc[i][j] = __builtin_amdgcn_mfma_f32_16x16x32_f16(af[i], bf[j], acc[i][j], 0, 0, 0);
    __syncthreads();   // before next-tile staging overwrites LDS
  }

  const long coff = (long)z * sC;
#pragma unroll
  for (int i = 0; i < FM; ++i)
#pragma unroll
    for (int j = 0; j < FN; ++j)
#pragma unroll
      for (int r = 0; r < 4; ++r) {
        const int row = m0 + wr * WM + i * 16 + g * 4 + r;   // C/D: row=(l>>4)*4+reg
        const int col = n0 + wc * WN + j * 16 + cc;          //      col=l&15
        float v = acc[i][j][r];
        if (MODE == 1) v = (v + bias[col]) * alpha;
        if (MODE == 2 || MODE == 4) v = v + rowscale[row] * bias[col];
        if (MODE == 3) {
          const int nb = gridDim.z / SK;   // batches
          ((float*)Cv)[((long)ks * nb + z) * sC + (long)row * ldc + col] = v;
        } else if (MODE == 4) {
          ((half_t*)Cv)[coff + (long)(col >> 6) * ((long)M * 64) + (long)row * 64 + (col & 63)]
              = (half_t)v;
        } else {
          if (OUTF16) ((half_t*)Cv)[coff + (long)row * ldc + col] = (half_t)v;
          else        ((float*)Cv)[coff + (long)row * ldc + col] = v;
        }
      }
}

// ---------------------------------------------------------------------------
// Fused attention v4: LDS-staged K/V per (b,h) block (swizzled, coalesced
// global_load_lds), flash-chunked swapped QK^T -> online softmax -> PV.
// kE head-blocked [b][h][256][64]; vFt [b][h][64][256] (head-contiguous).
// 512 threads (8 waves x 32 qrows = 256 qrows/block). One barrier total.
// ---------------------------------------------------------------------------
__global__ __launch_bounds__(512, 2)
void attn_fused(const half_t* __restrict__ q, const half_t* __restrict__ kEh,
                const half_t* __restrict__ vFt, half_t* __restrict__ outp, int L)
{
  __shared__ __attribute__((aligned(16))) half_t Ks[256 * 64];  // 32KB
  __shared__ __attribute__((aligned(16))) half_t Vs[64 * 256];  // 32KB
  const int tid = threadIdx.x, w = tid >> 6, lane = tid & 63;
  const int g = lane >> 4, c = lane & 15;
  const int l0 = blockIdx.x * 256, h = blockIdx.y, b = blockIdx.z;

  const half_t* keh = kEh + (long)(b * 16 + h) * 16384;   // [256][64]
  const half_t* vfh = vFt + (long)b * 262144 + (long)h * 16384;  // [64][256]
  const half_t* qb  = q + ((long)b * L + l0 + w * 32) * 1024 + h * 64;
  half_t* ob = outp + ((long)b * L + l0 + w * 32) * 1024 + h * 64;

  // stage kE: linear LDS dest, inverse-swizzled source (16B slots, xor row&7)
#pragma unroll
  for (int i = 0; i < 4; ++i) {
    const int row = i * 64 + (tid >> 3), slot = tid & 7;
    gload_lds16(keh + row * 64 + ((slot ^ (row & 7)) << 3),
                (char*)Ks + i * 8192 + tid * 16);
  }
  // stage vFt: rows of 512B = 32 slots of 16B, same xor on low 3 slot bits
#pragma unroll
  for (int i = 0; i < 4; ++i) {
    const int row = i * 16 + (tid >> 5), slot = tid & 31;
    gload_lds16(vfh + row * 256 + ((slot ^ (row & 7)) << 3),
                (char*)Vs + i * 8192 + tid * 16);
  }

  // q as B-operand fragments (n = qrow_local = fi*16 + c, k = d) — global read
  f16x8 qf[2][2];
#pragma unroll
  for (int fi = 0; fi < 2; ++fi)
#pragma unroll
    for (int ks = 0; ks < 2; ++ks)
      qf[fi][ks] = *(const f16x8*)(qb + (long)(fi * 16 + c) * 1024 + ks * 32 + g * 8);

  __syncthreads();   // staged K/V visible

  const f32x4 zero = {0.f, 0.f, 0.f, 0.f};
  f32x4 o[2][4];
#pragma unroll
  for (int fi = 0; fi < 2; ++fi)
#pragma unroll
    for (int fd = 0; fd < 4; ++fd) o[fi][fd] = zero;
  float mrun[2] = {-3.0e38f, -3.0e38f};
  float lrun[2] = {0.f, 0.f};

  for (int ch = 0; ch < 4; ++ch) {
    // --- QK^T chunk from LDS: S^T = kE · q^T, keys = ch*64 + fj*16 + g*4 + r
    f32x4 s[2][4];
#pragma unroll
    for (int fi = 0; fi < 2; ++fi)
#pragma unroll
      for (int fj = 0; fj < 4; ++fj) s[fi][fj] = zero;
#pragma unroll
    for (int fj = 0; fj < 4; ++fj) {
      const int krow = ch * 64 + fj * 16 + c;
      const char* kb = (const char*)Ks + krow * 128;
      f16x8 k0 = *(const f16x8*)(kb + ((g ^ (c & 7)) << 4));
      f16x8 k1 = *(const f16x8*)(kb + (((4 + g) ^ (c & 7)) << 4));
#pragma unroll
      for (int fi = 0; fi < 2; ++fi) {
        s[fi][fj] = __builtin_amdgcn_mfma_f32_16x16x32_f16(k0, qf[fi][0], s[fi][fj], 0, 0, 0);
        s[fi][fj] = __builtin_amdgcn_mfma_f32_16x16x32_f16(k1, qf[fi][1], s[fi][fj], 0, 0, 0);
      }
    }

    // --- online softmax update (per fi; qrow = col c; reduce across g) ---
    f16x4 p[2][4];
#pragma unroll
    for (int fi = 0; fi < 2; ++fi) {
      float cm = -3.0e38f;
#pragma unroll
      for (int fj = 0; fj < 4; ++fj)
#pragma unroll
        for (int r = 0; r < 4; ++r) cm = fmaxf(cm, s[fi][fj][r]);
      cm = fmaxf(cm, __shfl_xor(cm, 16));
      cm = fmaxf(cm, __shfl_xor(cm, 32));
      const float mnew = fmaxf(mrun[fi], cm);
      const float sc = __expf(mrun[fi] - mnew);   // 0 on first chunk
      float csum = 0.f;
#pragma unroll
      for (int fj = 0; fj < 4; ++fj) {
        f16x4 fr;
#pragma unroll
        for (int r = 0; r < 4; ++r) {
          float e = __expf(s[fi][fj][r] - mnew);
          fr[r] = (half_t)e; csum += e;
        }
        p[fi][fj] = fr;
      }
      csum += __shfl_xor(csum, 16);
      csum += __shfl_xor(csum, 32);
      lrun[fi] = lrun[fi] * sc + csum;
      mrun[fi] = mnew;
#pragma unroll
      for (int fd = 0; fd < 4; ++fd)
#pragma unroll
        for (int r = 0; r < 4; ++r) o[fi][fd][r] *= sc;
    }

    // --- PV chunk from LDS: OUT^T += vFt · P^T (K=16 per mfma) ---
#pragma unroll
    for (int kc = 0; kc < 4; ++kc) {
      const int s16 = ch * 8 + kc * 2 + (g >> 1);
      f16x4 va[4];
#pragma unroll
      for (int fd = 0; fd < 4; ++fd) {
        const int drow = fd * 16 + c;
        va[fd] = *(const f16x4*)((const char*)Vs + drow * 512 +
                                 ((s16 ^ (c & 7)) << 4) + (g & 1) * 8);
      }
#pragma unroll
      for (int fi = 0; fi < 2; ++fi)
#pragma unroll
        for (int fd = 0; fd < 4; ++fd)
          o[fi][fd] = __builtin_amdgcn_mfma_f32_16x16x16f16(va[fd], p[fi][kc], o[fi][fd], 0, 0, 0);
    }
  }

  // store OUT^T * 1/l: row = d = fd*16 + g*4 + r (contiguous -> 8B), col = qrow
#pragma unroll
  for (int fi = 0; fi < 2; ++fi) {
    const float inv = 1.0f / lrun[fi];
#pragma unroll
    for (int fd = 0; fd < 4; ++fd) {
      f16x4 st;
#pragma unroll
      for (int r = 0; r < 4; ++r) st[r] = (half_t)(o[fi][fd][r] * inv);
      *(f16x4*)(ob + (long)(fi * 16 + c) * 1024 + fd * 16 + g * 4) = st;
    }
  }
}

// ---------------------------------------------------------------------------
// helpers
// ---------------------------------------------------------------------------
// sum 8 split-K f32 partial slices [8][4][512][1024] -> fp16 [4][512][1024]
__global__ void reduce8_f16(const float* __restrict__ in, half_t* __restrict__ out) {
  long i = ((long)blockIdx.x * 256 + threadIdx.x) * 4;   // over 2,097,152 elems
  float4v a = *(const float4v*)(in + i);
#pragma unroll
  for (int ks = 1; ks < 8; ++ks) {
    float4v t = *(const float4v*)(in + (long)ks * 2097152 + i);
    a.x += t.x; a.y += t.y; a.z += t.z; a.w += t.w;
  }
  f16x4 o;
  o[0] = (half_t)a.x; o[1] = (half_t)a.y; o[2] = (half_t)a.z; o[3] = (half_t)a.w;
  *(f16x4*)(out + i) = o;
}

// x [4][4096][1024] f32 -> xhf fp16 (same layout) AND xT [4][1024][4096] fp16
__global__ void xpass(const float* __restrict__ x, half_t* __restrict__ xhf,
                      half_t* __restrict__ xT) {
  __shared__ float t[32][33];
  const int b = blockIdx.z, d0 = blockIdx.x * 32, l0 = blockIdx.y * 32;
  const int tx = threadIdx.x, ty = threadIdx.y;
  const float* ip = x + ((long)b * 4096 + l0) * 1024 + d0;
  half_t* oh = xhf + ((long)b * 4096 + l0) * 1024 + d0;
#pragma unroll
  for (int j = 0; j < 4; ++j) {
    float v = ip[(long)(ty + 8 * j) * 1024 + tx];
    t[ty + 8 * j][tx] = v;
    oh[(long)(ty + 8 * j) * 1024 + tx] = (half_t)v;
  }
  __syncthreads();
  half_t* ot = xT + ((long)b * 1024 + d0) * 4096 + l0;
#pragma unroll
  for (int j = 0; j < 4; ++j)
    ot[(long)(ty + 8 * j) * 4096 + tx] = (half_t)t[tx][ty + 8 * j];
}

// E [4096][256] f32 -> E^T [256][4096] fp16, plus colsum(E) -> ssum[256]
__global__ void efpass(const float* __restrict__ in, half_t* __restrict__ outT,
                       float* __restrict__ ssum) {
  __shared__ float t[32][33];
  __shared__ float ps[8][32];
  const int k0 = blockIdx.x * 32, l0 = blockIdx.y * 32;
  const int tx = threadIdx.x, ty = threadIdx.y;
  float p = 0.f;
#pragma unroll
  for (int j = 0; j < 4; ++j) {
    float v = in[(long)(l0 + ty + 8 * j) * 256 + k0 + tx];
    t[ty + 8 * j][tx] = v; p += v;
  }
  ps[ty][tx] = p;
  __syncthreads();
  if (ty == 0) {
    float a = 0.f;
#pragma unroll
    for (int r = 0; r < 8; ++r) a += ps[r][tx];
    atomicAdd(&ssum[k0 + tx], a);
  }
#pragma unroll
  for (int j = 0; j < 4; ++j)
    outT[(long)(k0 + ty + 8 * j) * 4096 + l0 + tx] = (half_t)t[tx][ty + 8 * j];
}

__global__ void transpose_f32_f16(const float* __restrict__ in, half_t* __restrict__ out,
                                  int R, int C) {
  __shared__ float t[32][33];
  const int cx = blockIdx.x * 32 + threadIdx.x;
  const int r0 = blockIdx.y * 32;
#pragma unroll
  for (int j = 0; j < 4; ++j)
    t[threadIdx.y + 8 * j][threadIdx.x] = in[(long)(r0 + threadIdx.y + 8 * j) * C + cx];
  __syncthreads();
  const int rx = r0 + threadIdx.x;
  const int cy = blockIdx.x * 32 + threadIdx.y;
#pragma unroll
  for (int j = 0; j < 4; ++j)
    out[(long)(cy + 8 * j) * R + rx] = (half_t)t[threadIdx.x][threadIdx.y + 8 * j];
}

// ---------------------------------------------------------------------------
extern "C" void kernel_launch(void* const* d_in, const int* in_sizes, int n_in,
                              void* d_out, int out_size, void* d_ws, size_t ws_size,
                              hipStream_t stream)
{
  const float* x  = (const float*)d_in[0];
  const float* Wq = (const float*)d_in[1];
  const float* bq = (const float*)d_in[2];
  const float* Wk = (const float*)d_in[3];
  const float* bk = (const float*)d_in[4];
  const float* Wv = (const float*)d_in[5];
  const float* bv = (const float*)d_in[6];
  const float* E  = (const float*)d_in[7];
  const float* F  = (const float*)d_in[8];
  const float* Wo = (const float*)d_in[9];
  const float* bo = (const float*)d_in[10];
  float* out = (float*)d_out;

  char* ws = (char*)d_ws;
  half_t* xhf  = (half_t*)(ws);                 // 33.5MB; later reused as out_pre
  half_t* xT   = (half_t*)(ws + 33554432);      // 33.5MB (dead after xEF gemm)
  half_t* qhf  = (half_t*)(ws + 67108864);      // 33.5MB
  half_t* Wqt  = (half_t*)(ws + 100663296);
  half_t* Wkt  = Wqt + 1048576;
  half_t* Wvt  = Wkt + 1048576;
  half_t* Wot  = Wvt + 1048576;
  half_t* EFt  = (half_t*)(ws + 109051904);     // [512][4096]: E^T on top of F^T
  half_t* xEF  = (half_t*)(ws + 113246208);     // per b: [512][1024] = [xE; xF]
  half_t* kEb  = (half_t*)(ws + 117440512);     // per b: [16][256][64] head-blocked
  half_t* vFtb = (half_t*)(ws + 119537664);     // per b: [1024][256] (= [16][64][256])
  float*  sEF  = (float*)(ws + 121634816);      // sE[256], sF[256]
  half_t* outp = xhf;                           // out_pre overlays x_f16
  float*  xEFf = (float*)d_out;                 // 67MB split-K partials [8][4][512][1024]
                                                // in d_out (overwritten by final GEMM)

  hipMemsetAsync(sEF, 0, 2048, stream);
  dim3 tb(32, 8);
  xpass<<<dim3(32, 128, 4), tb, 0, stream>>>(x, xhf, xT);
  efpass<<<dim3(8, 128, 1), tb, 0, stream>>>(E, EFt, sEF);
  efpass<<<dim3(8, 128, 1), tb, 0, stream>>>(F, EFt + 1048576, sEF + 256);
  transpose_f32_f16<<<dim3(32, 32, 1), tb, 0, stream>>>(Wq, Wqt, 1024, 1024);
  transpose_f32_f16<<<dim3(32, 32, 1), tb, 0, stream>>>(Wk, Wkt, 1024, 1024);
  transpose_f32_f16<<<dim3(32, 32, 1), tb, 0, stream>>>(Wv, Wvt, 1024, 1024);
  transpose_f32_f16<<<dim3(32, 32, 1), tb, 0, stream>>>(Wo, Wot, 1024, 1024);

  // xEF partials: [E^T; F^T] @ x_b  (M=512, N=1024, K=4096) split-K=8, plain f32
  gemm_bt<128,128,64,64,0,3,8><<<dim3(4, 8, 32), 256, 0, stream>>>(
      EFt, xT, (void*)xEFf, nullptr, nullptr, 512, 1024, 4096, 4096, 4096, 1024, 1.f,
      0, 4194304, 524288);
  reduce8_f16<<<2048, 256, 0, stream>>>(xEFf, xEF);

  // q = (x@Wq + bq) * hd^-0.5  -> fp16 [16384][1024]
  gemm_bt<128,128,64,64,1,1,1><<<dim3(128, 8, 1), 256, 0, stream>>>(
      xhf, Wqt, qhf, bq, nullptr, 16384, 1024, 1024, 1024, 1024, 1024, 0.125f, 0, 0, 0);
  // kE[b] = xE_b @ Wk + sE*bk  -> head-blocked [b][16][256][64]  (MODE 4)
  gemm_bt<128,128,64,64,1,4,1><<<dim3(2, 8, 4), 256, 0, stream>>>(
      xEF, Wkt, kEb, bk, sEF, 256, 1024, 1024, 1024, 1024, 1024, 1.f,
      524288, 0, 262144);
  // vFt[b] = Wv^T @ xF_b^T + bv*sF  (M=1024, N=256, K=1024) -> [b][16][64][256]
  gemm_bt<128,128,64,64,1,2,1><<<dim3(8, 2, 4), 256, 0, stream>>>(
      Wvt, xEF + 262144, vFtb, sEF + 256, bv, 1024, 256, 1024, 1024, 1024, 256, 1.f,
      0, 524288, 262144);
  // fused qk^T -> softmax -> PV   (writes out_pre fp16 [b][l][h*64+d])
  attn_fused<<<dim3(16, 16, 4), 512, 0, stream>>>(qhf, kEb, vFtb, outp, 4096);
  // out = out_pre @ Wo + bo  (fp32)
  gemm_bt<128,128,64,64,0,1,1><<<dim3(128, 8, 1), 256, 0, stream>>>(
      outp, Wot, (void*)out, bo, nullptr, 16384, 1024, 1024, 1024, 1024, 1024, 1.f, 0, 0, 0);
  (void)in_sizes; (void)n_in; (void)out_size; (void)ws_size;
}

// Round 9
// 251.621 us; speedup vs baseline: 1.4376x; 1.0615x over previous
//
#include <hip/hip_runtime.h>

typedef _Float16 half_t;
typedef __attribute__((ext_vector_type(8))) _Float16 f16x8;   // 8 fp16 = 4 VGPRs
typedef __attribute__((ext_vector_type(4))) _Float16 f16x4;
typedef __attribute__((ext_vector_type(4))) float f32x4;
typedef __attribute__((ext_vector_type(4))) float float4v;

__device__ __forceinline__ void gload_lds16(const void* g, void* l) {
  __builtin_amdgcn_global_load_lds(
      (const __attribute__((address_space(1))) void*)g,
      (__attribute__((address_space(3))) void*)l, 16, 0, 0);
}

// ---------------------------------------------------------------------------
// Big-GEMM: C[16384][1024] = A[16384][1024] * B, Bt given (B^T [1024][1024]).
// 256x128 tile, BK=32, 8 waves (4M x 2N), 3-deep pipelined LDS (72KB),
// counted vmcnt (T4), XOR-swizzled LDS (T2), setprio around MFMA (T5).
// Epilogue: C = (acc + bias[col]) * alpha, f16 or f32 out.
// ---------------------------------------------------------------------------
template<int OUTF16>
__global__ __launch_bounds__(512, 2)
void gemm_big(const half_t* __restrict__ A, const half_t* __restrict__ Bt,
              void* __restrict__ Cv, const float* __restrict__ bias, float alpha)
{
  // per buffer (24KB): A-tile [256][32] at +0 (16KB), B-tile [128][32] at +16KB
  __shared__ __attribute__((aligned(16))) char lds[73728];
  const int tid = threadIdx.x, w = tid >> 6, lane = tid & 63;
  const int wr = w >> 1, wc = w & 1;          // wave grid 4M x 2N
  const int g = lane >> 4, cc = lane & 15;
  const int m0 = blockIdx.x * 256, n0 = blockIdx.y * 128;

  // staging map: thread covers row sr, swizzled 16B slot (ss ^ ((sr>>1)&3))
  const int sr = tid >> 2, ss = tid & 3;
  const long aoff = (long)(m0 + sr) * 1024 + ((ss ^ ((sr >> 1) & 3)) << 3);
  const long boff = (long)(n0 + sr) * 1024 + ((ss ^ ((sr >> 1) & 3)) << 3);
  const int dst = tid * 16;

  char* b0 = lds;            // tile t (compute)
  char* b1 = lds + 24576;    // tile t+1
  char* b2 = lds + 49152;    // tile t+2 (staging target)

  const f32x4 zero = {0.f, 0.f, 0.f, 0.f};
  f32x4 acc[4][4];
#pragma unroll
  for (int i = 0; i < 4; ++i)
#pragma unroll
    for (int j = 0; j < 4; ++j) acc[i][j] = zero;

  auto STAGE = [&](int tau, char* bp) {
    const half_t* Ak = A + tau * 32;
    const half_t* Bk = Bt + tau * 32;
    gload_lds16(Ak + aoff,          bp + dst);          // A rows 0..127
    gload_lds16(Ak + aoff + 131072, bp + 8192 + dst);   // A rows 128..255
    gload_lds16(Bk + boff,          bp + 16384 + dst);  // B rows 0..127
  };

  STAGE(0, b0);
  STAGE(1, b1);
  asm volatile("s_waitcnt vmcnt(3)" ::: "memory");   // tile0 landed; tile1 in flight
  __builtin_amdgcn_s_barrier();
  __builtin_amdgcn_sched_barrier(0);

  const int aslot = (g ^ ((cc >> 1) & 3)) << 4;  // swizzled 16B slot (same A and B)
  const int arow = wr * 64 + cc;
  const int brow = wc * 64 + cc;

#pragma unroll 1
  for (int t = 0; t < 32; ++t) {
    if (t < 30) STAGE(t + 2, b2);
    f16x8 af[4], bf[4];
#pragma unroll
    for (int mf = 0; mf < 4; ++mf)
      af[mf] = *(const f16x8*)(b0 + (arow + mf * 16) * 64 + aslot);
#pragma unroll
    for (int nf = 0; nf < 4; ++nf)
      bf[nf] = *(const f16x8*)(b0 + 16384 + (brow + nf * 16) * 64 + aslot);
    __builtin_amdgcn_s_setprio(1);
#pragma unroll
    for (int mf = 0; mf < 4; ++mf)
#pragma unroll
      for (int nf = 0; nf < 4; ++nf)
        acc[mf][nf] = __builtin_amdgcn_mfma_f32_16x16x32_f16(af[mf], bf[nf], acc[mf][nf], 0, 0, 0);
    __builtin_amdgcn_s_setprio(0);
    __builtin_amdgcn_sched_barrier(0);
    if (t == 31) break;
    if (t < 30) { asm volatile("s_waitcnt vmcnt(3)" ::: "memory"); }  // t+1 landed, t+2 flying
    else        { asm volatile("s_waitcnt vmcnt(0)" ::: "memory"); }  // tail drain
    __builtin_amdgcn_s_barrier();
    __builtin_amdgcn_sched_barrier(0);
    char* tmp = b0; b0 = b1; b1 = b2; b2 = tmp;
  }

#pragma unroll
  for (int mf = 0; mf < 4; ++mf)
#pragma unroll
    for (int nf = 0; nf < 4; ++nf)
#pragma unroll
      for (int r = 0; r < 4; ++r) {
        const int row = m0 + wr * 64 + mf * 16 + g * 4 + r;   // D: row=(l>>4)*4+reg
        const int col = n0 + wc * 64 + nf * 16 + cc;          //    col=l&15
        float v = (acc[mf][nf][r] + bias[col]) * alpha;
        if (OUTF16) ((half_t*)Cv)[(long)row * 1024 + col] = (half_t)v;
        else        ((float*)Cv)[(long)row * 1024 + col] = v;
      }
}

// ---------------------------------------------------------------------------
// General tiled GEMM (128x128, m97-structure) for the small/odd shapes.
// MODE 0: C = acc ; MODE 1: C = (acc + bias[col]) * alpha
// MODE 2: C = acc + rowscale[row] * bias[col]
// MODE 3: split-K partials, plain f32 stores to slice ks
// MODE 4: MODE2 value, stored head-blocked: [col/64][row][col&63] (fp16)
// ---------------------------------------------------------------------------
template<int BM, int BN, int WM, int WN, int OUTF16, int MODE, int SK>
__global__ __launch_bounds__(256, 2)
void gemm_bt(const half_t* __restrict__ A, const half_t* __restrict__ Bt,
             void* __restrict__ Cv, const float* __restrict__ bias,
             const float* __restrict__ rowscale,
             int M, int N, int K, int lda, int ldb, int ldc, float alpha,
             long sA, long sB, long sC)
{
  constexpr int FM = WM / 16, FN = WN / 16, CW = BN / WN;
  __shared__ __attribute__((aligned(16))) half_t As[BM * 32];
  __shared__ __attribute__((aligned(16))) half_t Bs[BN * 32];

  const int tid = threadIdx.x, w = tid >> 6, lane = tid & 63;
  const int wr = w / CW, wc = w % CW;
  const int z = blockIdx.z / SK, ks = blockIdx.z % SK;
  const half_t* Ab = A + (long)z * sA;
  const half_t* Bb = Bt + (long)z * sB;
  const int m0 = blockIdx.x * BM, n0 = blockIdx.y * BN;
  const int g = lane >> 4, cc = lane & 15;
  const int srow = lane >> 2, scol = (lane & 3) * 8;   // staging lane map

  const f32x4 zero = {0.f, 0.f, 0.f, 0.f};
  f32x4 acc[FM][FN];
#pragma unroll
  for (int i = 0; i < FM; ++i)
#pragma unroll
    for (int j = 0; j < FN; ++j) acc[i][j] = zero;

  const int kchunk = K / SK;
  for (int kt = ks * kchunk; kt < (ks + 1) * kchunk; kt += 32) {
#pragma unroll
    for (int j = 0; j < BM / 64; ++j) {
      const int bi = w * (BM / 64) + j;
      gload_lds16(Ab + (long)(m0 + bi * 16 + srow) * lda + kt + scol, &As[bi * 512]);
    }
#pragma unroll
    for (int j = 0; j < BN / 64; ++j) {
      const int bi = w * (BN / 64) + j;
      gload_lds16(Bb + (long)(n0 + bi * 16 + srow) * ldb + kt + scol, &Bs[bi * 512]);
    }
    __syncthreads();   // drains vmcnt -> staged data visible

    f16x8 af[FM], bf[FN];
#pragma unroll
    for (int i = 0; i < FM; ++i)
      af[i] = *(const f16x8*)&As[(wr * WM + i * 16 + cc) * 32 + g * 8];
#pragma unroll
    for (int j = 0; j < FN; ++j)
      bf[j] = *(const f16x8*)&Bs[(wc * WN + j * 16 + cc) * 32 + g * 8];
#pragma unroll
    for (int i = 0; i < FM; ++i)
#pragma unroll
      for (int j = 0; j < FN; ++j)
        acc[i][j] = __builtin_amdgcn_mfma_f32_16x16x32_f16(af[i], bf[j], acc[i][j], 0, 0, 0);
    __syncthreads();   // before next-tile staging overwrites LDS
  }

  const long coff = (long)z * sC;
#pragma unroll
  for (int i = 0; i < FM; ++i)
#pragma unroll
    for (int j = 0; j < FN; ++j)
#pragma unroll
      for (int r = 0; r < 4; ++r) {
        const int row = m0 + wr * WM + i * 16 + g * 4 + r;   // C/D: row=(l>>4)*4+reg
        const int col = n0 + wc * WN + j * 16 + cc;          //      col=l&15
        float v = acc[i][j][r];
        if (MODE == 1) v = (v + bias[col]) * alpha;
        if (MODE == 2 || MODE == 4) v = v + rowscale[row] * bias[col];
        if (MODE == 3) {
          const int nb = gridDim.z / SK;   // batches
          ((float*)Cv)[((long)ks * nb + z) * sC + (long)row * ldc + col] = v;
        } else if (MODE == 4) {
          ((half_t*)Cv)[coff + (long)(col >> 6) * ((long)M * 64) + (long)row * 64 + (col & 63)]
              = (half_t)v;
        } else {
          if (OUTF16) ((half_t*)Cv)[coff + (long)row * ldc + col] = (half_t)v;
          else        ((float*)Cv)[coff + (long)row * ldc + col] = v;
        }
      }
}

// ---------------------------------------------------------------------------
// Fused attention v4: LDS-staged K/V per (b,h) block (swizzled, coalesced
// global_load_lds), flash-chunked swapped QK^T -> online softmax -> PV.
// ---------------------------------------------------------------------------
__global__ __launch_bounds__(512, 2)
void attn_fused(const half_t* __restrict__ q, const half_t* __restrict__ kEh,
                const half_t* __restrict__ vFt, half_t* __restrict__ outp, int L)
{
  __shared__ __attribute__((aligned(16))) half_t Ks[256 * 64];  // 32KB
  __shared__ __attribute__((aligned(16))) half_t Vs[64 * 256];  // 32KB
  const int tid = threadIdx.x, w = tid >> 6, lane = tid & 63;
  const int g = lane >> 4, c = lane & 15;
  const int l0 = blockIdx.x * 256, h = blockIdx.y, b = blockIdx.z;

  const half_t* keh = kEh + (long)(b * 16 + h) * 16384;   // [256][64]
  const half_t* vfh = vFt + (long)b * 262144 + (long)h * 16384;  // [64][256]
  const half_t* qb  = q + ((long)b * L + l0 + w * 32) * 1024 + h * 64;
  half_t* ob = outp + ((long)b * L + l0 + w * 32) * 1024 + h * 64;

  // stage kE: linear LDS dest, inverse-swizzled source (16B slots, xor row&7)
#pragma unroll
  for (int i = 0; i < 4; ++i) {
    const int row = i * 64 + (tid >> 3), slot = tid & 7;
    gload_lds16(keh + row * 64 + ((slot ^ (row & 7)) << 3),
                (char*)Ks + i * 8192 + tid * 16);
  }
  // stage vFt: rows of 512B = 32 slots of 16B, same xor on low 3 slot bits
#pragma unroll
  for (int i = 0; i < 4; ++i) {
    const int row = i * 16 + (tid >> 5), slot = tid & 31;
    gload_lds16(vfh + row * 256 + ((slot ^ (row & 7)) << 3),
                (char*)Vs + i * 8192 + tid * 16);
  }

  // q as B-operand fragments (n = qrow_local = fi*16 + c, k = d) — global read
  f16x8 qf[2][2];
#pragma unroll
  for (int fi = 0; fi < 2; ++fi)
#pragma unroll
    for (int ks = 0; ks < 2; ++ks)
      qf[fi][ks] = *(const f16x8*)(qb + (long)(fi * 16 + c) * 1024 + ks * 32 + g * 8);

  __syncthreads();   // staged K/V visible

  const f32x4 zero = {0.f, 0.f, 0.f, 0.f};
  f32x4 o[2][4];
#pragma unroll
  for (int fi = 0; fi < 2; ++fi)
#pragma unroll
    for (int fd = 0; fd < 4; ++fd) o[fi][fd] = zero;
  float mrun[2] = {-3.0e38f, -3.0e38f};
  float lrun[2] = {0.f, 0.f};

  for (int ch = 0; ch < 4; ++ch) {
    // --- QK^T chunk from LDS: S^T = kE · q^T, keys = ch*64 + fj*16 + g*4 + r
    f32x4 s[2][4];
#pragma unroll
    for (int fi = 0; fi < 2; ++fi)
#pragma unroll
      for (int fj = 0; fj < 4; ++fj) s[fi][fj] = zero;
#pragma unroll
    for (int fj = 0; fj < 4; ++fj) {
      const int krow = ch * 64 + fj * 16 + c;
      const char* kb = (const char*)Ks + krow * 128;
      f16x8 k0 = *(const f16x8*)(kb + ((g ^ (c & 7)) << 4));
      f16x8 k1 = *(const f16x8*)(kb + (((4 + g) ^ (c & 7)) << 4));
#pragma unroll
      for (int fi = 0; fi < 2; ++fi) {
        s[fi][fj] = __builtin_amdgcn_mfma_f32_16x16x32_f16(k0, qf[fi][0], s[fi][fj], 0, 0, 0);
        s[fi][fj] = __builtin_amdgcn_mfma_f32_16x16x32_f16(k1, qf[fi][1], s[fi][fj], 0, 0, 0);
      }
    }

    // --- online softmax update (per fi; qrow = col c; reduce across g) ---
    f16x4 p[2][4];
#pragma unroll
    for (int fi = 0; fi < 2; ++fi) {
      float cm = -3.0e38f;
#pragma unroll
      for (int fj = 0; fj < 4; ++fj)
#pragma unroll
        for (int r = 0; r < 4; ++r) cm = fmaxf(cm, s[fi][fj][r]);
      cm = fmaxf(cm, __shfl_xor(cm, 16));
      cm = fmaxf(cm, __shfl_xor(cm, 32));
      const float mnew = fmaxf(mrun[fi], cm);
      const float sc = __expf(mrun[fi] - mnew);   // 0 on first chunk
      float csum = 0.f;
#pragma unroll
      for (int fj = 0; fj < 4; ++fj) {
        f16x4 fr;
#pragma unroll
        for (int r = 0; r < 4; ++r) {
          float e = __expf(s[fi][fj][r] - mnew);
          fr[r] = (half_t)e; csum += e;
        }
        p[fi][fj] = fr;
      }
      csum += __shfl_xor(csum, 16);
      csum += __shfl_xor(csum, 32);
      lrun[fi] = lrun[fi] * sc + csum;
      mrun[fi] = mnew;
#pragma unroll
      for (int fd = 0; fd < 4; ++fd)
#pragma unroll
        for (int r = 0; r < 4; ++r) o[fi][fd][r] *= sc;
    }

    // --- PV chunk from LDS: OUT^T += vFt · P^T (K=16 per mfma) ---
#pragma unroll
    for (int kc = 0; kc < 4; ++kc) {
      const int s16 = ch * 8 + kc * 2 + (g >> 1);
      f16x4 va[4];
#pragma unroll
      for (int fd = 0; fd < 4; ++fd) {
        const int drow = fd * 16 + c;
        va[fd] = *(const f16x4*)((const char*)Vs + drow * 512 +
                                 ((s16 ^ (c & 7)) << 4) + (g & 1) * 8);
      }
#pragma unroll
      for (int fi = 0; fi < 2; ++fi)
#pragma unroll
        for (int fd = 0; fd < 4; ++fd)
          o[fi][fd] = __builtin_amdgcn_mfma_f32_16x16x16f16(va[fd], p[fi][kc], o[fi][fd], 0, 0, 0);
    }
  }

  // store OUT^T * 1/l: row = d = fd*16 + g*4 + r (contiguous -> 8B), col = qrow
#pragma unroll
  for (int fi = 0; fi < 2; ++fi) {
    const float inv = 1.0f / lrun[fi];
#pragma unroll
    for (int fd = 0; fd < 4; ++fd) {
      f16x4 st;
#pragma unroll
      for (int r = 0; r < 4; ++r) st[r] = (half_t)(o[fi][fd][r] * inv);
      *(f16x4*)(ob + (long)(fi * 16 + c) * 1024 + fd * 16 + g * 4) = st;
    }
  }
}

// ---------------------------------------------------------------------------
// helpers
// ---------------------------------------------------------------------------
// sum 4 split-K f32 partial slices [4][4][512][1024] -> fp16 [4][512][1024]
__global__ void reduce4_f16(const float* __restrict__ in, half_t* __restrict__ out) {
  long i = ((long)blockIdx.x * 256 + threadIdx.x) * 4;   // over 2,097,152 elems
  float4v a = *(const float4v*)(in + i);
#pragma unroll
  for (int ks = 1; ks < 4; ++ks) {
    float4v t = *(const float4v*)(in + (long)ks * 2097152 + i);
    a.x += t.x; a.y += t.y; a.z += t.z; a.w += t.w;
  }
  f16x4 o;
  o[0] = (half_t)a.x; o[1] = (half_t)a.y; o[2] = (half_t)a.z; o[3] = (half_t)a.w;
  *(f16x4*)(out + i) = o;
}

// x [4][4096][1024] f32 -> xhf fp16 (same layout) AND xT [4][1024][4096] fp16
__global__ void xpass(const float* __restrict__ x, half_t* __restrict__ xhf,
                      half_t* __restrict__ xT) {
  __shared__ float t[32][33];
  const int b = blockIdx.z, d0 = blockIdx.x * 32, l0 = blockIdx.y * 32;
  const int tx = threadIdx.x, ty = threadIdx.y;
  const float* ip = x + ((long)b * 4096 + l0) * 1024 + d0;
  half_t* oh = xhf + ((long)b * 4096 + l0) * 1024 + d0;
#pragma unroll
  for (int j = 0; j < 4; ++j) {
    float v = ip[(long)(ty + 8 * j) * 1024 + tx];
    t[ty + 8 * j][tx] = v;
    oh[(long)(ty + 8 * j) * 1024 + tx] = (half_t)v;
  }
  __syncthreads();
  half_t* ot = xT + ((long)b * 1024 + d0) * 4096 + l0;
#pragma unroll
  for (int j = 0; j < 4; ++j)
    ot[(long)(ty + 8 * j) * 4096 + tx] = (half_t)t[tx][ty + 8 * j];
}

// E [4096][256] f32 -> E^T [256][4096] fp16, plus colsum(E) -> ssum[256]
__global__ void efpass(const float* __restrict__ in, half_t* __restrict__ outT,
                       float* __restrict__ ssum) {
  __shared__ float t[32][33];
  __shared__ float ps[8][32];
  const int k0 = blockIdx.x * 32, l0 = blockIdx.y * 32;
  const int tx = threadIdx.x, ty = threadIdx.y;
  float p = 0.f;
#pragma unroll
  for (int j = 0; j < 4; ++j) {
    float v = in[(long)(l0 + ty + 8 * j) * 256 + k0 + tx];
    t[ty + 8 * j][tx] = v; p += v;
  }
  ps[ty][tx] = p;
  __syncthreads();
  if (ty == 0) {
    float a = 0.f;
#pragma unroll
    for (int r = 0; r < 8; ++r) a += ps[r][tx];
    atomicAdd(&ssum[k0 + tx], a);
  }
#pragma unroll
  for (int j = 0; j < 4; ++j)
    outT[(long)(k0 + ty + 8 * j) * 4096 + l0 + tx] = (half_t)t[tx][ty + 8 * j];
}

__global__ void transpose_f32_f16(const float* __restrict__ in, half_t* __restrict__ out,
                                  int R, int C) {
  __shared__ float t[32][33];
  const int cx = blockIdx.x * 32 + threadIdx.x;
  const int r0 = blockIdx.y * 32;
#pragma unroll
  for (int j = 0; j < 4; ++j)
    t[threadIdx.y + 8 * j][threadIdx.x] = in[(long)(r0 + threadIdx.y + 8 * j) * C + cx];
  __syncthreads();
  const int rx = r0 + threadIdx.x;
  const int cy = blockIdx.x * 32 + threadIdx.y;
#pragma unroll
  for (int j = 0; j < 4; ++j)
    out[(long)(cy + 8 * j) * R + rx] = (half_t)t[threadIdx.x][threadIdx.y + 8 * j];
}

// ---------------------------------------------------------------------------
extern "C" void kernel_launch(void* const* d_in, const int* in_sizes, int n_in,
                              void* d_out, int out_size, void* d_ws, size_t ws_size,
                              hipStream_t stream)
{
  const float* x  = (const float*)d_in[0];
  const float* Wq = (const float*)d_in[1];
  const float* bq = (const float*)d_in[2];
  const float* Wk = (const float*)d_in[3];
  const float* bk = (const float*)d_in[4];
  const float* Wv = (const float*)d_in[5];
  const float* bv = (const float*)d_in[6];
  const float* E  = (const float*)d_in[7];
  const float* F  = (const float*)d_in[8];
  const float* Wo = (const float*)d_in[9];
  const float* bo = (const float*)d_in[10];
  float* out = (float*)d_out;

  char* ws = (char*)d_ws;
  half_t* xhf  = (half_t*)(ws);                 // 33.5MB; later reused as out_pre
  half_t* xT   = (half_t*)(ws + 33554432);      // 33.5MB (dead after xEF gemm)
  half_t* qhf  = (half_t*)(ws + 67108864);      // 33.5MB
  half_t* Wqt  = (half_t*)(ws + 100663296);
  half_t* Wkt  = Wqt + 1048576;
  half_t* Wvt  = Wkt + 1048576;
  half_t* Wot  = Wvt + 1048576;
  half_t* EFt  = (half_t*)(ws + 109051904);     // [512][4096]: E^T on top of F^T
  half_t* xEF  = (half_t*)(ws + 113246208);     // per b: [512][1024] = [xE; xF]
  half_t* kEb  = (half_t*)(ws + 117440512);     // per b: [16][256][64] head-blocked
  half_t* vFtb = (half_t*)(ws + 119537664);     // per b: [1024][256] (= [16][64][256])
  float*  sEF  = (float*)(ws + 121634816);      // sE[256], sF[256]
  half_t* outp = xhf;                           // out_pre overlays x_f16
  float*  xEFf = (float*)d_out;                 // 33.5MB split-K partials [4][4][512][1024]
                                                // in d_out (overwritten by final GEMM)

  hipMemsetAsync(sEF, 0, 2048, stream);
  dim3 tb(32, 8);
  xpass<<<dim3(32, 128, 4), tb, 0, stream>>>(x, xhf, xT);
  efpass<<<dim3(8, 128, 1), tb, 0, stream>>>(E, EFt, sEF);
  efpass<<<dim3(8, 128, 1), tb, 0, stream>>>(F, EFt + 1048576, sEF + 256);
  transpose_f32_f16<<<dim3(32, 32, 1), tb, 0, stream>>>(Wq, Wqt, 1024, 1024);
  transpose_f32_f16<<<dim3(32, 32, 1), tb, 0, stream>>>(Wk, Wkt, 1024, 1024);
  transpose_f32_f16<<<dim3(32, 32, 1), tb, 0, stream>>>(Wv, Wvt, 1024, 1024);
  transpose_f32_f16<<<dim3(32, 32, 1), tb, 0, stream>>>(Wo, Wot, 1024, 1024);

  // xEF partials: [E^T; F^T] @ x_b  (M=512, N=1024, K=4096) split-K=4, plain f32
  gemm_bt<128,128,64,64,0,3,4><<<dim3(4, 8, 16), 256, 0, stream>>>(
      EFt, xT, (void*)xEFf, nullptr, nullptr, 512, 1024, 4096, 4096, 4096, 1024, 1.f,
      0, 4194304, 524288);
  reduce4_f16<<<2048, 256, 0, stream>>>(xEFf, xEF);

  // q = (x@Wq + bq) * hd^-0.5  -> fp16 [16384][1024]  (pipelined big-GEMM)
  gemm_big<1><<<dim3(64, 8), 512, 0, stream>>>(xhf, Wqt, qhf, bq, 0.125f);
  // kE[b] = xE_b @ Wk + sE*bk  -> head-blocked [b][16][256][64]  (MODE 4)
  gemm_bt<128,128,64,64,1,4,1><<<dim3(2, 8, 4), 256, 0, stream>>>(
      xEF, Wkt, kEb, bk, sEF, 256, 1024, 1024, 1024, 1024, 1024, 1.f,
      524288, 0, 262144);
  // vFt[b] = Wv^T @ xF_b^T + bv*sF  (M=1024, N=256, K=1024) -> [b][16][64][256]
  gemm_bt<128,128,64,64,1,2,1><<<dim3(8, 2, 4), 256, 0, stream>>>(
      Wvt, xEF + 262144, vFtb, sEF + 256, bv, 1024, 256, 1024, 1024, 1024, 256, 1.f,
      0, 524288, 262144);
  // fused qk^T -> softmax -> PV   (writes out_pre fp16 [b][l][h*64+d])
  attn_fused<<<dim3(16, 16, 4), 512, 0, stream>>>(qhf, kEb, vFtb, outp, 4096);
  // out = out_pre @ Wo + bo  (fp32, pipelined big-GEMM)
  gemm_big<0><<<dim3(64, 8), 512, 0, stream>>>(outp, Wot, (void*)out, bo, 1.0f);
  (void)in_sizes; (void)n_in; (void)out_size; (void)ws_size;
}

// Round 10
// 248.138 us; speedup vs baseline: 1.4578x; 1.0140x over previous
//
#include <hip/hip_runtime.h>

typedef _Float16 half_t;
typedef __attribute__((ext_vector_type(8))) _Float16 f16x8;   // 8 fp16 = 4 VGPRs
typedef __attribute__((ext_vector_type(4))) _Float16 f16x4;
typedef __attribute__((ext_vector_type(4))) float f32x4;
typedef __attribute__((ext_vector_type(4))) float float4v;

__device__ __forceinline__ void gload_lds16(const void* g, void* l) {
  __builtin_amdgcn_global_load_lds(
      (const __attribute__((address_space(1))) void*)g,
      (__attribute__((address_space(3))) void*)l, 16, 0, 0);
}

// ---------------------------------------------------------------------------
// Big-GEMM v2: C[16384][1024] = A[16384][1024] * B, Bt = B^T [1024][1024].
// 256x256 tile, BK=32, 8 waves (2M x 4N, each wave 128x64 = 32 MFMA/K-step),
// 4-deep pipelined LDS (128KB, 1 block/CU), counted vmcnt(8) -> ~2 iters of
// prefetch slack, XOR-swizzled LDS (T2), setprio around MFMA (T5).
// Epilogue: C = (acc + bias[col]) * alpha, f16 or f32 out.
// ---------------------------------------------------------------------------
template<int OUTF16>
__global__ __launch_bounds__(512, 2)
void gemm_big(const half_t* __restrict__ A, const half_t* __restrict__ Bt,
              void* __restrict__ Cv, const float* __restrict__ bias, float alpha)
{
  // per buffer (32KB): A-tile [256][32] at +0 (16KB), B-tile [256][32] at +16KB
  __shared__ __attribute__((aligned(16))) char lds[131072];
  const int tid = threadIdx.x, w = tid >> 6, lane = tid & 63;
  const int wr = w >> 2, wc = w & 3;          // wave grid 2M x 4N
  const int g = lane >> 4, cc = lane & 15;
  const int m0 = blockIdx.x * 256, n0 = blockIdx.y * 256;

  // staging: thread -> row sr (128/pass), 16B slot ss, source swizzled slot
  const int sr = tid >> 2, ss = tid & 3;
  const int swz = (ss ^ ((sr >> 1) & 3)) << 3;   // fp16 elems
  const long aoff = (long)(m0 + sr) * 1024 + swz;
  const long boff = (long)(n0 + sr) * 1024 + swz;
  const int dst = tid * 16;

  char* b0 = lds;             // tile t (compute)
  char* b1 = lds + 32768;     // t+1
  char* b2 = lds + 65536;     // t+2
  char* b3 = lds + 98304;     // t+3 (staging target)

  const f32x4 zero = {0.f, 0.f, 0.f, 0.f};
  f32x4 acc[8][4];
#pragma unroll
  for (int i = 0; i < 8; ++i)
#pragma unroll
    for (int j = 0; j < 4; ++j) acc[i][j] = zero;

  auto STAGE = [&](int tau, char* bp) {
    const half_t* Ak = A + tau * 32;
    const half_t* Bk = Bt + tau * 32;
    gload_lds16(Ak + aoff,          bp + dst);           // A rows   0..127
    gload_lds16(Ak + aoff + 131072, bp + 8192 + dst);    // A rows 128..255
    gload_lds16(Bk + boff,          bp + 16384 + dst);   // B rows   0..127
    gload_lds16(Bk + boff + 131072, bp + 24576 + dst);   // B rows 128..255
  };

  STAGE(0, b0);
  STAGE(1, b1);
  STAGE(2, b2);
  asm volatile("s_waitcnt vmcnt(8)" ::: "memory");   // tile0 landed; t1,t2 flying
  __builtin_amdgcn_s_barrier();
  __builtin_amdgcn_sched_barrier(0);

  const int aslot = (g ^ ((cc >> 1) & 3)) << 4;  // swizzled 16B slot (A and B)
  const int arow = wr * 128 + cc;
  const int brow = wc * 64 + cc;

#pragma unroll 1
  for (int t = 0; t < 32; ++t) {
    if (t < 29) STAGE(t + 3, b3);
    f16x8 af[8], bf[4];
#pragma unroll
    for (int mf = 0; mf < 8; ++mf)
      af[mf] = *(const f16x8*)(b0 + (arow + mf * 16) * 64 + aslot);
#pragma unroll
    for (int nf = 0; nf < 4; ++nf)
      bf[nf] = *(const f16x8*)(b0 + 16384 + (brow + nf * 16) * 64 + aslot);
    __builtin_amdgcn_s_setprio(1);
#pragma unroll
    for (int mf = 0; mf < 8; ++mf)
#pragma unroll
      for (int nf = 0; nf < 4; ++nf)
        acc[mf][nf] = __builtin_amdgcn_mfma_f32_16x16x32_f16(af[mf], bf[nf], acc[mf][nf], 0, 0, 0);
    __builtin_amdgcn_s_setprio(0);
    __builtin_amdgcn_sched_barrier(0);
    if (t == 31) break;
    if (t < 29)       { asm volatile("s_waitcnt vmcnt(8)" ::: "memory"); }  // t+1 landed
    else if (t == 29) { asm volatile("s_waitcnt vmcnt(4)" ::: "memory"); }
    else              { asm volatile("s_waitcnt vmcnt(0)" ::: "memory"); }
    __builtin_amdgcn_s_barrier();
    __builtin_amdgcn_sched_barrier(0);
    char* tmp = b0; b0 = b1; b1 = b2; b2 = b3; b3 = tmp;
  }

#pragma unroll
  for (int mf = 0; mf < 8; ++mf)
#pragma unroll
    for (int nf = 0; nf < 4; ++nf)
#pragma unroll
      for (int r = 0; r < 4; ++r) {
        const int row = m0 + wr * 128 + mf * 16 + g * 4 + r;  // D: row=(l>>4)*4+reg
        const int col = n0 + wc * 64 + nf * 16 + cc;          //    col=l&15
        float v = (acc[mf][nf][r] + bias[col]) * alpha;
        if (OUTF16) ((half_t*)Cv)[(long)row * 1024 + col] = (half_t)v;
        else        ((float*)Cv)[(long)row * 1024 + col] = v;
      }
}

// ---------------------------------------------------------------------------
// General tiled GEMM (128x128, m97-structure) for the small/odd shapes.
// MODE 0: C = acc ; MODE 1: C = (acc + bias[col]) * alpha
// MODE 2: C = acc + rowscale[row] * bias[col]
// MODE 3: split-K partials, plain f32 stores to slice ks
// MODE 4: MODE2 value, stored head-blocked: [col/64][row][col&63] (fp16)
// ---------------------------------------------------------------------------
template<int BM, int BN, int WM, int WN, int OUTF16, int MODE, int SK>
__global__ __launch_bounds__(256, 2)
void gemm_bt(const half_t* __restrict__ A, const half_t* __restrict__ Bt,
             void* __restrict__ Cv, const float* __restrict__ bias,
             const float* __restrict__ rowscale,
             int M, int N, int K, int lda, int ldb, int ldc, float alpha,
             long sA, long sB, long sC)
{
  constexpr int FM = WM / 16, FN = WN / 16, CW = BN / WN;
  __shared__ __attribute__((aligned(16))) half_t As[BM * 32];
  __shared__ __attribute__((aligned(16))) half_t Bs[BN * 32];

  const int tid = threadIdx.x, w = tid >> 6, lane = tid & 63;
  const int wr = w / CW, wc = w % CW;
  const int z = blockIdx.z / SK, ks = blockIdx.z % SK;
  const half_t* Ab = A + (long)z * sA;
  const half_t* Bb = Bt + (long)z * sB;
  const int m0 = blockIdx.x * BM, n0 = blockIdx.y * BN;
  const int g = lane >> 4, cc = lane & 15;
  const int srow = lane >> 2, scol = (lane & 3) * 8;   // staging lane map

  const f32x4 zero = {0.f, 0.f, 0.f, 0.f};
  f32x4 acc[FM][FN];
#pragma unroll
  for (int i = 0; i < FM; ++i)
#pragma unroll
    for (int j = 0; j < FN; ++j) acc[i][j] = zero;

  const int kchunk = K / SK;
  for (int kt = ks * kchunk; kt < (ks + 1) * kchunk; kt += 32) {
#pragma unroll
    for (int j = 0; j < BM / 64; ++j) {
      const int bi = w * (BM / 64) + j;
      gload_lds16(Ab + (long)(m0 + bi * 16 + srow) * lda + kt + scol, &As[bi * 512]);
    }
#pragma unroll
    for (int j = 0; j < BN / 64; ++j) {
      const int bi = w * (BN / 64) + j;
      gload_lds16(Bb + (long)(n0 + bi * 16 + srow) * ldb + kt + scol, &Bs[bi * 512]);
    }
    __syncthreads();   // drains vmcnt -> staged data visible

    f16x8 af[FM], bf[FN];
#pragma unroll
    for (int i = 0; i < FM; ++i)
      af[i] = *(const f16x8*)&As[(wr * WM + i * 16 + cc) * 32 + g * 8];
#pragma unroll
    for (int j = 0; j < FN; ++j)
      bf[j] = *(const f16x8*)&Bs[(wc * WN + j * 16 + cc) * 32 + g * 8];
#pragma unroll
    for (int i = 0; i < FM; ++i)
#pragma unroll
      for (int j = 0; j < FN; ++j)
        acc[i][j] = __builtin_amdgcn_mfma_f32_16x16x32_f16(af[i], bf[j], acc[i][j], 0, 0, 0);
    __syncthreads();   // before next-tile staging overwrites LDS
  }

  const long coff = (long)z * sC;
#pragma unroll
  for (int i = 0; i < FM; ++i)
#pragma unroll
    for (int j = 0; j < FN; ++j)
#pragma unroll
      for (int r = 0; r < 4; ++r) {
        const int row = m0 + wr * WM + i * 16 + g * 4 + r;   // C/D: row=(l>>4)*4+reg
        const int col = n0 + wc * WN + j * 16 + cc;          //      col=l&15
        float v = acc[i][j][r];
        if (MODE == 1) v = (v + bias[col]) * alpha;
        if (MODE == 2 || MODE == 4) v = v + rowscale[row] * bias[col];
        if (MODE == 3) {
          const int nb = gridDim.z / SK;   // batches
          ((float*)Cv)[((long)ks * nb + z) * sC + (long)row * ldc + col] = v;
        } else if (MODE == 4) {
          ((half_t*)Cv)[coff + (long)(col >> 6) * ((long)M * 64) + (long)row * 64 + (col & 63)]
              = (half_t)v;
        } else {
          if (OUTF16) ((half_t*)Cv)[coff + (long)row * ldc + col] = (half_t)v;
          else        ((float*)Cv)[coff + (long)row * ldc + col] = v;
        }
      }
}

// ---------------------------------------------------------------------------
// Fused attention v4: LDS-staged K/V per (b,h) block (swizzled, coalesced
// global_load_lds), flash-chunked swapped QK^T -> online softmax -> PV.
// ---------------------------------------------------------------------------
__global__ __launch_bounds__(512, 2)
void attn_fused(const half_t* __restrict__ q, const half_t* __restrict__ kEh,
                const half_t* __restrict__ vFt, half_t* __restrict__ outp, int L)
{
  __shared__ __attribute__((aligned(16))) half_t Ks[256 * 64];  // 32KB
  __shared__ __attribute__((aligned(16))) half_t Vs[64 * 256];  // 32KB
  const int tid = threadIdx.x, w = tid >> 6, lane = tid & 63;
  const int g = lane >> 4, c = lane & 15;
  const int l0 = blockIdx.x * 256, h = blockIdx.y, b = blockIdx.z;

  const half_t* keh = kEh + (long)(b * 16 + h) * 16384;   // [256][64]
  const half_t* vfh = vFt + (long)b * 262144 + (long)h * 16384;  // [64][256]
  const half_t* qb  = q + ((long)b * L + l0 + w * 32) * 1024 + h * 64;
  half_t* ob = outp + ((long)b * L + l0 + w * 32) * 1024 + h * 64;

  // stage kE: linear LDS dest, inverse-swizzled source (16B slots, xor row&7)
#pragma unroll
  for (int i = 0; i < 4; ++i) {
    const int row = i * 64 + (tid >> 3), slot = tid & 7;
    gload_lds16(keh + row * 64 + ((slot ^ (row & 7)) << 3),
                (char*)Ks + i * 8192 + tid * 16);
  }
  // stage vFt: rows of 512B = 32 slots of 16B, same xor on low 3 slot bits
#pragma unroll
  for (int i = 0; i < 4; ++i) {
    const int row = i * 16 + (tid >> 5), slot = tid & 31;
    gload_lds16(vfh + row * 256 + ((slot ^ (row & 7)) << 3),
                (char*)Vs + i * 8192 + tid * 16);
  }

  // q as B-operand fragments (n = qrow_local = fi*16 + c, k = d) — global read
  f16x8 qf[2][2];
#pragma unroll
  for (int fi = 0; fi < 2; ++fi)
#pragma unroll
    for (int ks = 0; ks < 2; ++ks)
      qf[fi][ks] = *(const f16x8*)(qb + (long)(fi * 16 + c) * 1024 + ks * 32 + g * 8);

  __syncthreads();   // staged K/V visible

  const f32x4 zero = {0.f, 0.f, 0.f, 0.f};
  f32x4 o[2][4];
#pragma unroll
  for (int fi = 0; fi < 2; ++fi)
#pragma unroll
    for (int fd = 0; fd < 4; ++fd) o[fi][fd] = zero;
  float mrun[2] = {-3.0e38f, -3.0e38f};
  float lrun[2] = {0.f, 0.f};

  for (int ch = 0; ch < 4; ++ch) {
    // --- QK^T chunk from LDS: S^T = kE · q^T, keys = ch*64 + fj*16 + g*4 + r
    f32x4 s[2][4];
#pragma unroll
    for (int fi = 0; fi < 2; ++fi)
#pragma unroll
      for (int fj = 0; fj < 4; ++fj) s[fi][fj] = zero;
#pragma unroll
    for (int fj = 0; fj < 4; ++fj) {
      const int krow = ch * 64 + fj * 16 + c;
      const char* kb = (const char*)Ks + krow * 128;
      f16x8 k0 = *(const f16x8*)(kb + ((g ^ (c & 7)) << 4));
      f16x8 k1 = *(const f16x8*)(kb + (((4 + g) ^ (c & 7)) << 4));
#pragma unroll
      for (int fi = 0; fi < 2; ++fi) {
        s[fi][fj] = __builtin_amdgcn_mfma_f32_16x16x32_f16(k0, qf[fi][0], s[fi][fj], 0, 0, 0);
        s[fi][fj] = __builtin_amdgcn_mfma_f32_16x16x32_f16(k1, qf[fi][1], s[fi][fj], 0, 0, 0);
      }
    }

    // --- online softmax update (per fi; qrow = col c; reduce across g) ---
    f16x4 p[2][4];
#pragma unroll
    for (int fi = 0; fi < 2; ++fi) {
      float cm = -3.0e38f;
#pragma unroll
      for (int fj = 0; fj < 4; ++fj)
#pragma unroll
        for (int r = 0; r < 4; ++r) cm = fmaxf(cm, s[fi][fj][r]);
      cm = fmaxf(cm, __shfl_xor(cm, 16));
      cm = fmaxf(cm, __shfl_xor(cm, 32));
      const float mnew = fmaxf(mrun[fi], cm);
      const float sc = __expf(mrun[fi] - mnew);   // 0 on first chunk
      float csum = 0.f;
#pragma unroll
      for (int fj = 0; fj < 4; ++fj) {
        f16x4 fr;
#pragma unroll
        for (int r = 0; r < 4; ++r) {
          float e = __expf(s[fi][fj][r] - mnew);
          fr[r] = (half_t)e; csum += e;
        }
        p[fi][fj] = fr;
      }
      csum += __shfl_xor(csum, 16);
      csum += __shfl_xor(csum, 32);
      lrun[fi] = lrun[fi] * sc + csum;
      mrun[fi] = mnew;
#pragma unroll
      for (int fd = 0; fd < 4; ++fd)
#pragma unroll
        for (int r = 0; r < 4; ++r) o[fi][fd][r] *= sc;
    }

    // --- PV chunk from LDS: OUT^T += vFt · P^T (K=16 per mfma) ---
#pragma unroll
    for (int kc = 0; kc < 4; ++kc) {
      const int s16 = ch * 8 + kc * 2 + (g >> 1);
      f16x4 va[4];
#pragma unroll
      for (int fd = 0; fd < 4; ++fd) {
        const int drow = fd * 16 + c;
        va[fd] = *(const f16x4*)((const char*)Vs + drow * 512 +
                                 ((s16 ^ (c & 7)) << 4) + (g & 1) * 8);
      }
#pragma unroll
      for (int fi = 0; fi < 2; ++fi)
#pragma unroll
        for (int fd = 0; fd < 4; ++fd)
          o[fi][fd] = __builtin_amdgcn_mfma_f32_16x16x16f16(va[fd], p[fi][kc], o[fi][fd], 0, 0, 0);
    }
  }

  // store OUT^T * 1/l: row = d = fd*16 + g*4 + r (contiguous -> 8B), col = qrow
#pragma unroll
  for (int fi = 0; fi < 2; ++fi) {
    const float inv = 1.0f / lrun[fi];
#pragma unroll
    for (int fd = 0; fd < 4; ++fd) {
      f16x4 st;
#pragma unroll
      for (int r = 0; r < 4; ++r) st[r] = (half_t)(o[fi][fd][r] * inv);
      *(f16x4*)(ob + (long)(fi * 16 + c) * 1024 + fd * 16 + g * 4) = st;
    }
  }
}

// ---------------------------------------------------------------------------
// helpers
// ---------------------------------------------------------------------------
// sum 4 split-K f32 partial slices [4][4][512][1024] -> fp16 [4][512][1024]
__global__ void reduce4_f16(const float* __restrict__ in, half_t* __restrict__ out) {
  long i = ((long)blockIdx.x * 256 + threadIdx.x) * 4;   // over 2,097,152 elems
  float4v a = *(const float4v*)(in + i);
#pragma unroll
  for (int ks = 1; ks < 4; ++ks) {
    float4v t = *(const float4v*)(in + (long)ks * 2097152 + i);
    a.x += t.x; a.y += t.y; a.z += t.z; a.w += t.w;
  }
  f16x4 o;
  o[0] = (half_t)a.x; o[1] = (half_t)a.y; o[2] = (half_t)a.z; o[3] = (half_t)a.w;
  *(f16x4*)(out + i) = o;
}

// x [4][4096][1024] f32 -> xhf fp16 (same layout) AND xT [4][1024][4096] fp16
__global__ void xpass(const float* __restrict__ x, half_t* __restrict__ xhf,
                      half_t* __restrict__ xT) {
  __shared__ float t[32][33];
  const int b = blockIdx.z, d0 = blockIdx.x * 32, l0 = blockIdx.y * 32;
  const int tx = threadIdx.x, ty = threadIdx.y;
  const float* ip = x + ((long)b * 4096 + l0) * 1024 + d0;
  half_t* oh = xhf + ((long)b * 4096 + l0) * 1024 + d0;
#pragma unroll
  for (int j = 0; j < 4; ++j) {
    float v = ip[(long)(ty + 8 * j) * 1024 + tx];
    t[ty + 8 * j][tx] = v;
    oh[(long)(ty + 8 * j) * 1024 + tx] = (half_t)v;
  }
  __syncthreads();
  half_t* ot = xT + ((long)b * 1024 + d0) * 4096 + l0;
#pragma unroll
  for (int j = 0; j < 4; ++j)
    ot[(long)(ty + 8 * j) * 4096 + tx] = (half_t)t[tx][ty + 8 * j];
}

// E [4096][256] f32 -> E^T [256][4096] fp16, plus colsum(E) -> ssum[256]
__global__ void efpass(const float* __restrict__ in, half_t* __restrict__ outT,
                       float* __restrict__ ssum) {
  __shared__ float t[32][33];
  __shared__ float ps[8][32];
  const int k0 = blockIdx.x * 32, l0 = blockIdx.y * 32;
  const int tx = threadIdx.x, ty = threadIdx.y;
  float p = 0.f;
#pragma unroll
  for (int j = 0; j < 4; ++j) {
    float v = in[(long)(l0 + ty + 8 * j) * 256 + k0 + tx];
    t[ty + 8 * j][tx] = v; p += v;
  }
  ps[ty][tx] = p;
  __syncthreads();
  if (ty == 0) {
    float a = 0.f;
#pragma unroll
    for (int r = 0; r < 8; ++r) a += ps[r][tx];
    atomicAdd(&ssum[k0 + tx], a);
  }
#pragma unroll
  for (int j = 0; j < 4; ++j)
    outT[(long)(k0 + ty + 8 * j) * 4096 + l0 + tx] = (half_t)t[tx][ty + 8 * j];
}

__global__ void transpose_f32_f16(const float* __restrict__ in, half_t* __restrict__ out,
                                  int R, int C) {
  __shared__ float t[32][33];
  const int cx = blockIdx.x * 32 + threadIdx.x;
  const int r0 = blockIdx.y * 32;
#pragma unroll
  for (int j = 0; j < 4; ++j)
    t[threadIdx.y + 8 * j][threadIdx.x] = in[(long)(r0 + threadIdx.y + 8 * j) * C + cx];
  __syncthreads();
  const int rx = r0 + threadIdx.x;
  const int cy = blockIdx.x * 32 + threadIdx.y;
#pragma unroll
  for (int j = 0; j < 4; ++j)
    out[(long)(cy + 8 * j) * R + rx] = (half_t)t[threadIdx.x][threadIdx.y + 8 * j];
}

// ---------------------------------------------------------------------------
extern "C" void kernel_launch(void* const* d_in, const int* in_sizes, int n_in,
                              void* d_out, int out_size, void* d_ws, size_t ws_size,
                              hipStream_t stream)
{
  const float* x  = (const float*)d_in[0];
  const float* Wq = (const float*)d_in[1];
  const float* bq = (const float*)d_in[2];
  const float* Wk = (const float*)d_in[3];
  const float* bk = (const float*)d_in[4];
  const float* Wv = (const float*)d_in[5];
  const float* bv = (const float*)d_in[6];
  const float* E  = (const float*)d_in[7];
  const float* F  = (const float*)d_in[8];
  const float* Wo = (const float*)d_in[9];
  const float* bo = (const float*)d_in[10];
  float* out = (float*)d_out;

  char* ws = (char*)d_ws;
  half_t* xhf  = (half_t*)(ws);                 // 33.5MB; later reused as out_pre
  half_t* xT   = (half_t*)(ws + 33554432);      // 33.5MB (dead after xEF gemm)
  half_t* qhf  = (half_t*)(ws + 67108864);      // 33.5MB
  half_t* Wqt  = (half_t*)(ws + 100663296);
  half_t* Wkt  = Wqt + 1048576;
  half_t* Wvt  = Wkt + 1048576;
  half_t* Wot  = Wvt + 1048576;
  half_t* EFt  = (half_t*)(ws + 109051904);     // [512][4096]: E^T on top of F^T
  half_t* xEF  = (half_t*)(ws + 113246208);     // per b: [512][1024] = [xE; xF]
  half_t* kEb  = (half_t*)(ws + 117440512);     // per b: [16][256][64] head-blocked
  half_t* vFtb = (half_t*)(ws + 119537664);     // per b: [1024][256] (= [16][64][256])
  float*  sEF  = (float*)(ws + 121634816);      // sE[256], sF[256]
  half_t* outp = xhf;                           // out_pre overlays x_f16
  float*  xEFf = (float*)d_out;                 // 33.5MB split-K partials [4][4][512][1024]
                                                // in d_out (overwritten by final GEMM)

  hipMemsetAsync(sEF, 0, 2048, stream);
  dim3 tb(32, 8);
  xpass<<<dim3(32, 128, 4), tb, 0, stream>>>(x, xhf, xT);
  efpass<<<dim3(8, 128, 1), tb, 0, stream>>>(E, EFt, sEF);
  efpass<<<dim3(8, 128, 1), tb, 0, stream>>>(F, EFt + 1048576, sEF + 256);
  transpose_f32_f16<<<dim3(32, 32, 1), tb, 0, stream>>>(Wq, Wqt, 1024, 1024);
  transpose_f32_f16<<<dim3(32, 32, 1), tb, 0, stream>>>(Wk, Wkt, 1024, 1024);
  transpose_f32_f16<<<dim3(32, 32, 1), tb, 0, stream>>>(Wv, Wvt, 1024, 1024);
  transpose_f32_f16<<<dim3(32, 32, 1), tb, 0, stream>>>(Wo, Wot, 1024, 1024);

  // xEF partials: [E^T; F^T] @ x_b  (M=512, N=1024, K=4096) split-K=4, plain f32
  gemm_bt<128,128,64,64,0,3,4><<<dim3(4, 8, 16), 256, 0, stream>>>(
      EFt, xT, (void*)xEFf, nullptr, nullptr, 512, 1024, 4096, 4096, 4096, 1024, 1.f,
      0, 4194304, 524288);
  reduce4_f16<<<2048, 256, 0, stream>>>(xEFf, xEF);

  // q = (x@Wq + bq) * hd^-0.5  -> fp16 [16384][1024]  (pipelined big-GEMM v2)
  gemm_big<1><<<dim3(64, 4), 512, 0, stream>>>(xhf, Wqt, qhf, bq, 0.125f);
  // kE[b] = xE_b @ Wk + sE*bk  -> head-blocked [b][16][256][64]  (MODE 4)
  gemm_bt<128,128,64,64,1,4,1><<<dim3(2, 8, 4), 256, 0, stream>>>(
      xEF, Wkt, kEb, bk, sEF, 256, 1024, 1024, 1024, 1024, 1024, 1.f,
      524288, 0, 262144);
  // vFt[b] = Wv^T @ xF_b^T + bv*sF  (M=1024, N=256, K=1024) -> [b][16][64][256]
  gemm_bt<128,128,64,64,1,2,1><<<dim3(8, 2, 4), 256, 0, stream>>>(
      Wvt, xEF + 262144, vFtb, sEF + 256, bv, 1024, 256, 1024, 1024, 1024, 256, 1.f,
      0, 524288, 262144);
  // fused qk^T -> softmax -> PV   (writes out_pre fp16 [b][l][h*64+d])
  attn_fused<<<dim3(16, 16, 4), 512, 0, stream>>>(qhf, kEb, vFtb, outp, 4096);
  // out = out_pre @ Wo + bo  (fp32, pipelined big-GEMM v2)
  gemm_big<0><<<dim3(64, 4), 512, 0, stream>>>(outp, Wot, (void*)out, bo, 1.0f);
  (void)in_sizes; (void)n_in; (void)out_size; (void)ws_size;
}